// Round 1
// baseline (17116.621 us; speedup 1.0000x reference)
//
#include <hip/hip_runtime.h>
#include <stdint.h>
#include <string.h>

// ---------------- problem constants ----------------
#define T_ 64
#define B_ 256
#define XD_ 784
#define XDP_ 832   // XD padded to multiple of 64 for BK=64 staging
#define HD_ 2048
#define ZD_ 128
#define GD_ 6144   // 3*HD

typedef uint16_t u16;
typedef __attribute__((ext_vector_type(8))) short short8;
typedef __attribute__((ext_vector_type(4))) float floatx4;

enum { EPI_RELU_BF16 = 0, EPI_F32 = 1, EPI_ATOMF32 = 2, EPI_NLL = 3, EPI_GRU = 4, EPI_KLD = 5 };

struct GemmDesc {
  const u16* A0; const u16* A1; const float* Af;   // A1: concat-K second half; Af: f32 A (aF32) or x for NLL
  const u16* W0; const u16* W1;                    // W1: concat-N second half
  const float* bias0; const float* bias1;
  float* outF; u16* outB;
  const float* pf0; float* pf1; float* red;        // GRU: gi,gh ; KLD: pmps,emes ; red: atomic scalar
  int N, K, kSplit, nSplit, nValid;
  int lda0, lda1, ldw0, ldw1, ldo;
  int epi, aF32, blockStart, nTilesN;              // role blocks: nTilesN = raw block count
};
struct GemmArgs { GemmDesc d[6]; int n; };

struct ConvSeg { const float* src; u16* dst; int dR, dC, sR, sC; };
struct ConvArgs {
  ConvSeg s[15]; int n;
  float* hz; long hzN;     // zero h (f32)
  float* zf; long zfN;     // zero emes (f32)
  u16* zb; long zbN;       // zero h_bf
  float* out2;             // zero outputs
};

// ---------------- device helpers ----------------
__device__ __forceinline__ u16 f2bf(float f) {
  union { float f; uint32_t u; } c; c.f = f;
  return (u16)((c.u + 0x7fffu + ((c.u >> 16) & 1u)) >> 16);   // RNE
}
__device__ __forceinline__ float spf(float x) { return fmaxf(x, 0.f) + log1pf(expf(-fabsf(x))); }
__device__ __forceinline__ float sigf(float x) { return 1.f / (1.f + expf(-x)); }

__device__ __forceinline__ void gl_lds16(const void* g, void* l) {
  // async global->LDS, 16B per lane; LDS dest is wave-uniform base + lane*16
  __builtin_amdgcn_global_load_lds((__attribute__((address_space(1))) void*)(uintptr_t)g,
                                   (__attribute__((address_space(3))) void*)(uintptr_t)l, 16, 0, 0);
}

// ---------------- weight/x conversion + zero-init (runs every call; ws is re-poisoned) ----------------
__global__ void k_convert(ConvArgs a) {
  const long gid = (long)blockIdx.x * blockDim.x + threadIdx.x;
  const long stride = (long)gridDim.x * blockDim.x;
  for (int s = 0; s < a.n; ++s) {
    ConvSeg g = a.s[s];
    const long tot = (long)g.dR * g.dC;
    if (g.sR == g.dR && g.sC == g.dC) {
      const long nv = tot >> 3;
      const floatx4* s4 = (const floatx4*)g.src;
      for (long i = gid; i < nv; i += stride) {
        floatx4 x0 = s4[2 * i], x1 = s4[2 * i + 1];
        short8 v;
        v[0] = (short)f2bf(x0[0]); v[1] = (short)f2bf(x0[1]); v[2] = (short)f2bf(x0[2]); v[3] = (short)f2bf(x0[3]);
        v[4] = (short)f2bf(x1[0]); v[5] = (short)f2bf(x1[1]); v[6] = (short)f2bf(x1[2]); v[7] = (short)f2bf(x1[3]);
        *(short8*)&g.dst[i * 8] = v;
      }
    } else {
      for (long i = gid; i < tot; i += stride) {
        const int r = (int)(i / g.dC), c = (int)(i - (long)r * g.dC);
        u16 v = 0;
        if (r < g.sR && c < g.sC) v = f2bf(g.src[(long)r * g.sC + c]);
        g.dst[i] = v;
      }
    }
  }
  for (long i = gid; i < a.hzN; i += stride) a.hz[i] = 0.f;
  for (long i = gid; i < a.zfN; i += stride) a.zf[i] = 0.f;
  for (long i = gid; i < a.zbN; i += stride) a.zb[i] = 0;
  if (gid == 0) { a.out2[0] = 0.f; a.out2[1] = 0.f; }
}

// ---------------- multi-descriptor GEMM (m97-style 2-phase, 64xBN tile, BK=64) ----------------
template <int BN>
__global__ __launch_bounds__(256)
void k_gemm(GemmArgs args) {
  __shared__ u16 smA[64 * 64];
  __shared__ u16 smB[BN * 64];
  __shared__ float rs[4];
  const int bid = blockIdx.x;
  int di = 0;
  while (di + 1 < args.n && bid >= args.d[di + 1].blockStart) ++di;
  const GemmDesc& d = args.d[di];
  const int tid = threadIdx.x, lane = tid & 63, wv = tid >> 6;

  if (d.epi == EPI_GRU) {   // elementwise GRU combine: h_new = (1-u)*n + u*h  (fp32 state)
    const int local = bid - d.blockStart;
    const long stride = (long)d.nTilesN * 256;
    for (long i = (long)local * 256 + tid; i < (long)B_ * HD_; i += stride) {
      const int m = (int)(i >> 11), j = (int)(i & (HD_ - 1));
      const float* gi = d.pf0 + (long)m * GD_;
      const float* gh = d.pf1 + (long)m * GD_;
      const float r = sigf(gi[j] + gh[j]);
      const float u = sigf(gi[HD_ + j] + gh[HD_ + j]);
      const float nn = tanhf(gi[2 * HD_ + j] + r * gh[2 * HD_ + j]);
      const float hv = d.outF[i];
      const float hn = (1.f - u) * nn + u * hv;
      d.outF[i] = hn;
      d.outB[i] = f2bf(hn);
    }
    return;
  }
  if (d.epi == EPI_KLD) {   // KL(enc||prior) over [B,ZD]; zero emes after read (next step's split-K atomics)
    const int local = bid - d.blockStart;
    const long stride = (long)d.nTilesN * 256;
    float sum = 0.f;
    for (long i = (long)local * 256 + tid; i < (long)B_ * ZD_; i += stride) {
      const int m = (int)(i >> 7), j = (int)(i & 127);
      const float* P = d.pf0 + m * 256;
      float* E = d.pf1 + m * 256;
      const float pm = P[j], psr = P[128 + j];
      const float em = E[j], esr = E[128 + j];
      const float ps = spf(psr), es = spf(esr);
      const float dmn = (em - pm) / ps, sr = es / ps;
      sum += dmn * dmn + sr * sr - 2.f * (logf(es) - logf(ps)) - 1.f;
      E[j] = 0.f; E[128 + j] = 0.f;
    }
    #pragma unroll
    for (int o = 32; o; o >>= 1) sum += __shfl_down(sum, o, 64);
    if (lane == 0) rs[wv] = sum;
    __syncthreads();
    if (tid == 0) atomicAdd(d.red, 0.5f * (rs[0] + rs[1] + rs[2] + rs[3]));
    return;
  }

  const int local = bid - d.blockStart;
  const int tm = local / d.nTilesN;
  const int tn = local - tm * d.nTilesN;
  const int mBase = tm * 64, nBase = tn * BN;

  const u16* Wr; const float* bias; int ldw; int bOff;
  if (nBase < d.nSplit) { Wr = d.W0 + (long)nBase * d.ldw0; ldw = d.ldw0; bias = d.bias0; bOff = nBase; }
  else { Wr = d.W1 + (long)(nBase - d.nSplit) * d.ldw1; ldw = d.ldw1; bias = d.bias1; bOff = nBase - d.nSplit; }

  const int wm = wv >> 1, wn = wv & 1;
  constexpr int FN = BN / 32;
  floatx4 acc[2][FN];
  #pragma unroll
  for (int a = 0; a < 2; ++a)
    #pragma unroll
    for (int b = 0; b < FN; ++b) acc[a][b] = (floatx4){0.f, 0.f, 0.f, 0.f};

  for (int k0 = 0; k0 < d.K; k0 += 64) {
    if (!d.aF32) {
      const u16* Ab; int lda;
      if (k0 < d.kSplit) { Ab = d.A0 + k0; lda = d.lda0; }
      else { Ab = d.A1 + (k0 - d.kSplit); lda = d.lda1; }
      #pragma unroll
      for (int it = 0; it < 2; ++it) {
        const int e = it * 2048 + wv * 512 + lane * 8;
        const int r = e >> 6, c = e & 63;
        gl_lds16(Ab + (long)(mBase + r) * lda + c, smA + it * 2048 + wv * 512);
      }
    } else {   // fp32 A (x): load, convert, ds_write; zero-pad cols >= XD_
      #pragma unroll
      for (int it = 0; it < 2; ++it) {
        const int e = it * 2048 + wv * 512 + lane * 8;
        const int r = e >> 6, c = e & 63;
        const int gm = mBase + r, cb = k0 + c;
        float t[8];
        if (cb + 8 <= XD_) {
          const floatx4* p = (const floatx4*)(d.Af + (long)gm * XD_ + cb);
          floatx4 a0 = p[0], a1 = p[1];
          t[0] = a0[0]; t[1] = a0[1]; t[2] = a0[2]; t[3] = a0[3];
          t[4] = a1[0]; t[5] = a1[1]; t[6] = a1[2]; t[7] = a1[3];
        } else {
          #pragma unroll
          for (int j = 0; j < 8; ++j) t[j] = (cb + j < XD_) ? d.Af[(long)gm * XD_ + cb + j] : 0.f;
        }
        short8 v;
        #pragma unroll
        for (int j = 0; j < 8; ++j) v[j] = (short)f2bf(t[j]);
        *(short8*)&smA[e] = v;
      }
    }
    #pragma unroll
    for (int it = 0; it < FN; ++it) {
      const int e = it * 2048 + wv * 512 + lane * 8;
      const int r = e >> 6, c = e & 63;
      gl_lds16(Wr + (long)r * ldw + k0 + c, smB + it * 2048 + wv * 512);
    }
    __syncthreads();
    #pragma unroll
    for (int ks = 0; ks < 2; ++ks) {
      const int ko = ks * 32 + (lane >> 4) * 8;
      short8 af0 = *(const short8*)&smA[(wm * 32 + (lane & 15)) * 64 + ko];
      short8 af1 = *(const short8*)&smA[(wm * 32 + 16 + (lane & 15)) * 64 + ko];
      #pragma unroll
      for (int fn = 0; fn < FN; ++fn) {
        short8 bf = *(const short8*)&smB[(wn * (BN / 2) + fn * 16 + (lane & 15)) * 64 + ko];
        acc[0][fn] = __builtin_amdgcn_mfma_f32_16x16x32_bf16(af0, bf, acc[0][fn], 0, 0, 0);
        acc[1][fn] = __builtin_amdgcn_mfma_f32_16x16x32_bf16(af1, bf, acc[1][fn], 0, 0, 0);
      }
    }
    __syncthreads();
  }

  // epilogue: C/D layout col=lane&15, row=(lane>>4)*4+reg  [verified mapping]
  float nllSum = 0.f;
  #pragma unroll
  for (int fm = 0; fm < 2; ++fm)
    #pragma unroll
    for (int fn = 0; fn < FN; ++fn)
      #pragma unroll
      for (int j = 0; j < 4; ++j) {
        const int row = wm * 32 + fm * 16 + (lane >> 4) * 4 + j;
        const int col = wn * (BN / 2) + fn * 16 + (lane & 15);
        const int gm = mBase + row, gn = nBase + col;
        if (gn >= d.nValid) continue;
        float v = acc[fm][fn][j];
        if (bias) v += bias[bOff + col];
        switch (d.epi) {
          case EPI_RELU_BF16: d.outB[(long)gm * d.ldo + gn] = f2bf(fmaxf(v, 0.f)); break;
          case EPI_F32:       d.outF[(long)gm * d.ldo + gn] = v; break;
          case EPI_ATOMF32:   atomicAdd(&d.outF[(long)gm * d.ldo + gn], v); break;
          case EPI_NLL: {
            // dm = sigmoid(v); clip(log dm,-100) = -min(sp(-v),100); clip(log1p(-dm),-100) = -min(sp(v),100)
            const float xv = d.Af[(long)gm * XD_ + gn];
            nllSum += xv * fminf(spf(-v), 100.f) + (1.f - xv) * fminf(spf(v), 100.f);
          } break;
        }
      }
  if (d.epi == EPI_NLL) {
    #pragma unroll
    for (int o = 32; o; o >>= 1) nllSum += __shfl_down(nllSum, o, 64);
    if (lane == 0) rs[wv] = nllSum;
    __syncthreads();
    if (tid == 0) atomicAdd(d.red, rs[0] + rs[1] + rs[2] + rs[3]);
  }
}

// ---------------- fused z = eps*softplus(es)+em  ->  phi_z = relu(z@Wzp^T+bzp)  (K=128) ----------------
__global__ __launch_bounds__(256)
void k_phiz(const float* emes, const float* eps_t, const u16* Wzp, const float* bzp, u16* phiz) {
  __shared__ u16 zA[64 * 128];
  __shared__ u16 wB[128 * 128];
  const int bid = blockIdx.x;
  const int tm = bid >> 4, tn = bid & 15;
  const int mBase = tm * 64, nBase = tn * 128;
  const int tid = threadIdx.x, lane = tid & 63, wv = tid >> 6;
  for (int i = tid; i < 64 * 128; i += 256) {
    const int m = i >> 7, j = i & 127;
    const int gm = mBase + m;
    const float em = emes[gm * 256 + j];
    const float esr = emes[gm * 256 + 128 + j];
    zA[i] = f2bf(eps_t[(long)gm * 128 + j] * spf(esr) + em);
  }
  #pragma unroll
  for (int it = 0; it < 8; ++it) {
    const int e = it * 2048 + wv * 512 + lane * 8;
    const int r = e >> 7, c = e & 127;
    gl_lds16(Wzp + (long)(nBase + r) * 128 + c, wB + it * 2048 + wv * 512);
  }
  __syncthreads();
  const int wm = wv >> 1, wn = wv & 1;
  floatx4 acc[2][4];
  #pragma unroll
  for (int a = 0; a < 2; ++a)
    #pragma unroll
    for (int b = 0; b < 4; ++b) acc[a][b] = (floatx4){0.f, 0.f, 0.f, 0.f};
  #pragma unroll
  for (int ks = 0; ks < 4; ++ks) {
    const int ko = ks * 32 + (lane >> 4) * 8;
    short8 a0 = *(const short8*)&zA[(wm * 32 + (lane & 15)) * 128 + ko];
    short8 a1 = *(const short8*)&zA[(wm * 32 + 16 + (lane & 15)) * 128 + ko];
    #pragma unroll
    for (int fn = 0; fn < 4; ++fn) {
      short8 bf = *(const short8*)&wB[(wn * 64 + fn * 16 + (lane & 15)) * 128 + ko];
      acc[0][fn] = __builtin_amdgcn_mfma_f32_16x16x32_bf16(a0, bf, acc[0][fn], 0, 0, 0);
      acc[1][fn] = __builtin_amdgcn_mfma_f32_16x16x32_bf16(a1, bf, acc[1][fn], 0, 0, 0);
    }
  }
  #pragma unroll
  for (int fm = 0; fm < 2; ++fm)
    #pragma unroll
    for (int fn = 0; fn < 4; ++fn)
      #pragma unroll
      for (int j = 0; j < 4; ++j) {
        const int row = wm * 32 + fm * 16 + (lane >> 4) * 4 + j;
        const int col = wn * 64 + fn * 16 + (lane & 15);
        const int gm = mBase + row, gn = nBase + col;
        phiz[(long)gm * HD_ + gn] = f2bf(fmaxf(acc[fm][fn][j] + bzp[gn], 0.f));
      }
}

// ---------------- host ----------------
extern "C" void kernel_launch(void* const* d_in, const int* in_sizes, int n_in,
                              void* d_out, int out_size, void* d_ws, size_t ws_size,
                              hipStream_t stream) {
  const float* x   = (const float*)d_in[0];
  const float* eps = (const float*)d_in[1];
  const float* W1x = (const float*)d_in[2];  const float* b1x = (const float*)d_in[3];
  const float* W2x = (const float*)d_in[4];  const float* b2x = (const float*)d_in[5];
  const float* Wzp = (const float*)d_in[6];  const float* bzp = (const float*)d_in[7];
  const float* Wpr = (const float*)d_in[8];  const float* bpr = (const float*)d_in[9];
  const float* Wpm = (const float*)d_in[10]; const float* bpm = (const float*)d_in[11];
  const float* Wps = (const float*)d_in[12]; const float* bps = (const float*)d_in[13];
  const float* We1 = (const float*)d_in[14]; const float* be1 = (const float*)d_in[15];
  const float* We2 = (const float*)d_in[16]; const float* be2 = (const float*)d_in[17];
  const float* Wem = (const float*)d_in[18]; const float* bem = (const float*)d_in[19];
  const float* Wes = (const float*)d_in[20]; const float* bes = (const float*)d_in[21];
  const float* Wd1 = (const float*)d_in[22]; const float* bd1 = (const float*)d_in[23];
  const float* Wd2 = (const float*)d_in[24]; const float* bd2 = (const float*)d_in[25];
  const float* Wdm = (const float*)d_in[26]; const float* bdm = (const float*)d_in[27];
  const float* Wih = (const float*)d_in[28]; const float* bih = (const float*)d_in[29];
  const float* Whh = (const float*)d_in[30]; const float* bhh = (const float*)d_in[31];
  float* out = (float*)d_out;

  char* base = (char*)d_ws; size_t off = 0;
  auto alc = [&](size_t bytes) -> void* {
    void* r = base + off; off = (off + bytes + 255) & ~(size_t)255; return r;
  };
  // bf16 weights
  u16* W1xb = (u16*)alc((size_t)2048 * XDP_ * 2);
  u16* W2xb = (u16*)alc((size_t)2048 * 2048 * 2);
  u16* Wzpb = (u16*)alc((size_t)2048 * 128 * 2);
  u16* Wprb = (u16*)alc((size_t)2048 * 2048 * 2);
  u16* Wpmb = (u16*)alc((size_t)128 * 2048 * 2);
  u16* Wpsb = (u16*)alc((size_t)128 * 2048 * 2);
  u16* We1b = (u16*)alc((size_t)2048 * 4096 * 2);
  u16* We2b = (u16*)alc((size_t)2048 * 2048 * 2);
  u16* Wemb = (u16*)alc((size_t)128 * 2048 * 2);
  u16* Wesb = (u16*)alc((size_t)128 * 2048 * 2);
  u16* Wd1b = (u16*)alc((size_t)2048 * 4096 * 2);
  u16* Wd2b = (u16*)alc((size_t)2048 * 2048 * 2);
  u16* Wdmb = (u16*)alc((size_t)896 * 2048 * 2);   // N-padded 784->896, pad rows zero
  u16* Wihb = (u16*)alc((size_t)6144 * 4096 * 2);
  u16* Whhb = (u16*)alc((size_t)6144 * 2048 * 2);
  // activations
  u16* phixA   = (u16*)alc((size_t)B_ * HD_ * 2);
  u16* phixB   = (u16*)alc((size_t)B_ * HD_ * 2);
  u16* ph1     = (u16*)alc((size_t)B_ * HD_ * 2);
  float* h     = (float*)alc((size_t)B_ * HD_ * 4);
  u16* hbf     = (u16*)alc((size_t)B_ * HD_ * 2);
  u16* prior_bf= (u16*)alc((size_t)B_ * HD_ * 2);
  u16* enc1_bf = (u16*)alc((size_t)B_ * HD_ * 2);
  u16* enc_bf  = (u16*)alc((size_t)B_ * HD_ * 2);
  u16* dec1_bf = (u16*)alc((size_t)B_ * HD_ * 2);
  u16* dec_bf  = (u16*)alc((size_t)B_ * HD_ * 2);
  u16* phiz_bf = (u16*)alc((size_t)B_ * HD_ * 2);
  float* pmps  = (float*)alc((size_t)B_ * 256 * 4);
  float* emes  = (float*)alc((size_t)B_ * 256 * 4);
  float* gi    = (float*)alc((size_t)B_ * GD_ * 4);
  float* gh    = (float*)alc((size_t)B_ * GD_ * 4);
  if (off > ws_size) return;   // workspace too small -> loud validation failure, not corruption

  // ---- convert weights to bf16, zero h/h_bf/emes/out ----
  {
    ConvArgs ca; memset(&ca, 0, sizeof(ca));
    int ns = 0;
    auto seg = [&](const float* s, u16* dst, int dR, int dC, int sR, int sC) {
      ca.s[ns].src = s; ca.s[ns].dst = dst; ca.s[ns].dR = dR; ca.s[ns].dC = dC; ca.s[ns].sR = sR; ca.s[ns].sC = sC; ++ns;
    };
    seg(W1x, W1xb, 2048, XDP_, 2048, XD_);
    seg(W2x, W2xb, 2048, 2048, 2048, 2048);
    seg(Wzp, Wzpb, 2048, 128, 2048, 128);
    seg(Wpr, Wprb, 2048, 2048, 2048, 2048);
    seg(Wpm, Wpmb, 128, 2048, 128, 2048);
    seg(Wps, Wpsb, 128, 2048, 128, 2048);
    seg(We1, We1b, 2048, 4096, 2048, 4096);
    seg(We2, We2b, 2048, 2048, 2048, 2048);
    seg(Wem, Wemb, 128, 2048, 128, 2048);
    seg(Wes, Wesb, 128, 2048, 128, 2048);
    seg(Wd1, Wd1b, 2048, 4096, 2048, 4096);
    seg(Wd2, Wd2b, 2048, 2048, 2048, 2048);
    seg(Wdm, Wdmb, 896, 2048, 784, 2048);
    seg(Wih, Wihb, 6144, 4096, 6144, 4096);
    seg(Whh, Whhb, 6144, 2048, 6144, 2048);
    ca.n = ns;
    ca.hz = h;   ca.hzN = (long)B_ * HD_;
    ca.zf = emes; ca.zfN = (long)B_ * 256;
    ca.zb = hbf; ca.zbN = (long)B_ * HD_;
    ca.out2 = out;
    k_convert<<<1024, 256, 0, stream>>>(ca);
  }

  auto initD = [](GemmDesc& d) { memset(&d, 0, sizeof(d)); d.kSplit = 1 << 30; };

  // ---- prologue: phi_x(0) ----
  {
    GemmArgs a; memset(&a, 0, sizeof(a));
    GemmDesc& d = a.d[0]; initD(d);
    d.aF32 = 1; d.Af = x; d.K = XDP_;
    d.W0 = W1xb; d.ldw0 = XDP_; d.bias0 = b1x;
    d.N = HD_; d.nSplit = HD_; d.nValid = HD_;
    d.outB = ph1; d.ldo = HD_; d.epi = EPI_RELU_BF16; d.blockStart = 0; d.nTilesN = 32;
    a.n = 1;
    k_gemm<64><<<128, 256, 0, stream>>>(a);
  }
  {
    GemmArgs a; memset(&a, 0, sizeof(a));
    GemmDesc& d = a.d[0]; initD(d);
    d.A0 = ph1; d.lda0 = HD_; d.K = HD_;
    d.W0 = W2xb; d.ldw0 = HD_; d.bias0 = b2x;
    d.N = HD_; d.nSplit = HD_; d.nValid = HD_;
    d.outB = phixA; d.ldo = HD_; d.epi = EPI_RELU_BF16; d.blockStart = 0; d.nTilesN = 32;
    a.n = 1;
    k_gemm<64><<<128, 256, 0, stream>>>(a);
  }

  u16* phixCur = phixA; u16* phixNxt = phixB;
  for (int t = 0; t < T_; ++t) {
    // ---- S1: prior, enc1, gh  (+ dm/NLL of step t-1) ----
    {
      GemmArgs a; memset(&a, 0, sizeof(a));
      int bs = 0, n = 0;
      { GemmDesc& d = a.d[n++]; initD(d);
        d.A0 = hbf; d.lda0 = HD_; d.W0 = Wprb; d.ldw0 = HD_; d.bias0 = bpr;
        d.N = HD_; d.K = HD_; d.nSplit = HD_; d.nValid = HD_;
        d.outB = prior_bf; d.ldo = HD_; d.epi = EPI_RELU_BF16; d.blockStart = bs; d.nTilesN = 16; bs += 64; }
      { GemmDesc& d = a.d[n++]; initD(d);
        d.A0 = phixCur; d.lda0 = HD_; d.A1 = hbf; d.lda1 = HD_; d.kSplit = HD_;
        d.W0 = We1b; d.ldw0 = 4096; d.bias0 = be1;
        d.N = HD_; d.K = 4096; d.nSplit = HD_; d.nValid = HD_;
        d.outB = enc1_bf; d.ldo = HD_; d.epi = EPI_RELU_BF16; d.blockStart = bs; d.nTilesN = 16; bs += 64; }
      { GemmDesc& d = a.d[n++]; initD(d);
        d.A0 = hbf; d.lda0 = HD_; d.W0 = Whhb; d.ldw0 = HD_; d.bias0 = bhh;
        d.N = GD_; d.K = HD_; d.nSplit = GD_; d.nValid = GD_;
        d.outF = gh; d.ldo = GD_; d.epi = EPI_F32; d.blockStart = bs; d.nTilesN = 48; bs += 192; }
      if (t > 0) {
        GemmDesc& d = a.d[n++]; initD(d);
        d.A0 = dec_bf; d.lda0 = HD_; d.W0 = Wdmb; d.ldw0 = HD_; d.bias0 = bdm;
        d.N = 896; d.K = HD_; d.nSplit = 896; d.nValid = XD_;
        d.Af = x + (size_t)(t - 1) * B_ * XD_; d.red = out + 1;
        d.epi = EPI_NLL; d.blockStart = bs; d.nTilesN = 7; bs += 28;
      }
      a.n = n;
      k_gemm<128><<<bs, 256, 0, stream>>>(a);
    }
    // ---- S2: enc2, pm/ps ----
    {
      GemmArgs a; memset(&a, 0, sizeof(a));
      int bs = 0, n = 0;
      { GemmDesc& d = a.d[n++]; initD(d);
        d.A0 = enc1_bf; d.lda0 = HD_; d.W0 = We2b; d.ldw0 = HD_; d.bias0 = be2;
        d.N = HD_; d.K = HD_; d.nSplit = HD_; d.nValid = HD_;
        d.outB = enc_bf; d.ldo = HD_; d.epi = EPI_RELU_BF16; d.blockStart = bs; d.nTilesN = 32; bs += 128; }
      { GemmDesc& d = a.d[n++]; initD(d);
        d.A0 = prior_bf; d.lda0 = HD_;
        d.W0 = Wpmb; d.ldw0 = HD_; d.W1 = Wpsb; d.ldw1 = HD_; d.bias0 = bpm; d.bias1 = bps;
        d.N = 256; d.K = HD_; d.nSplit = 128; d.nValid = 256;
        d.outF = pmps; d.ldo = 256; d.epi = EPI_F32; d.blockStart = bs; d.nTilesN = 4; bs += 16; }
      a.n = n;
      k_gemm<64><<<bs, 256, 0, stream>>>(a);
    }
    // ---- S3: em/es (split-K x4, atomic into zeroed emes) ----
    {
      GemmArgs a; memset(&a, 0, sizeof(a));
      int bs = 0, n = 0;
      for (int c = 0; c < 4; ++c) {
        GemmDesc& d = a.d[n++]; initD(d);
        d.A0 = enc_bf + c * 512; d.lda0 = HD_;
        d.W0 = Wemb + c * 512; d.ldw0 = HD_; d.W1 = Wesb + c * 512; d.ldw1 = HD_;
        d.bias0 = (c == 0) ? bem : nullptr; d.bias1 = (c == 0) ? bes : nullptr;
        d.N = 256; d.K = 512; d.nSplit = 128; d.nValid = 256;
        d.outF = emes; d.ldo = 256; d.epi = EPI_ATOMF32; d.blockStart = bs; d.nTilesN = 4; bs += 16;
      }
      a.n = n;
      k_gemm<64><<<bs, 256, 0, stream>>>(a);
    }
    // ---- S4: z + phi_z ----
    k_phiz<<<64, 256, 0, stream>>>(emes, eps + (size_t)t * B_ * ZD_, Wzpb, bzp, phiz_bf);
    // ---- S5: dec1, gi  (+ phi_x stage1 for t+1) ----
    {
      GemmArgs a; memset(&a, 0, sizeof(a));
      int bs = 0, n = 0;
      { GemmDesc& d = a.d[n++]; initD(d);
        d.A0 = phiz_bf; d.lda0 = HD_; d.A1 = hbf; d.lda1 = HD_; d.kSplit = HD_;
        d.W0 = Wd1b; d.ldw0 = 4096; d.bias0 = bd1;
        d.N = HD_; d.K = 4096; d.nSplit = HD_; d.nValid = HD_;
        d.outB = dec1_bf; d.ldo = HD_; d.epi = EPI_RELU_BF16; d.blockStart = bs; d.nTilesN = 16; bs += 64; }
      { GemmDesc& d = a.d[n++]; initD(d);
        d.A0 = phixCur; d.lda0 = HD_; d.A1 = phiz_bf; d.lda1 = HD_; d.kSplit = HD_;
        d.W0 = Wihb; d.ldw0 = 4096; d.bias0 = bih;
        d.N = GD_; d.K = 4096; d.nSplit = GD_; d.nValid = GD_;
        d.outF = gi; d.ldo = GD_; d.epi = EPI_F32; d.blockStart = bs; d.nTilesN = 48; bs += 192; }
      if (t < T_ - 1) {
        GemmDesc& d = a.d[n++]; initD(d);
        d.aF32 = 1; d.Af = x + (size_t)(t + 1) * B_ * XD_; d.K = XDP_;
        d.W0 = W1xb; d.ldw0 = XDP_; d.bias0 = b1x;
        d.N = HD_; d.nSplit = HD_; d.nValid = HD_;
        d.outB = ph1; d.ldo = HD_; d.epi = EPI_RELU_BF16; d.blockStart = bs; d.nTilesN = 16; bs += 64;
      }
      a.n = n;
      k_gemm<128><<<bs, 256, 0, stream>>>(a);
    }
    // ---- S6: dec2, phi_x stage2 (t+1), GRU combine, KLD ----
    {
      GemmArgs a; memset(&a, 0, sizeof(a));
      int bs = 0, n = 0;
      { GemmDesc& d = a.d[n++]; initD(d);
        d.A0 = dec1_bf; d.lda0 = HD_; d.W0 = Wd2b; d.ldw0 = HD_; d.bias0 = bd2;
        d.N = HD_; d.K = HD_; d.nSplit = HD_; d.nValid = HD_;
        d.outB = dec_bf; d.ldo = HD_; d.epi = EPI_RELU_BF16; d.blockStart = bs; d.nTilesN = 32; bs += 128; }
      if (t < T_ - 1) {
        GemmDesc& d = a.d[n++]; initD(d);
        d.A0 = ph1; d.lda0 = HD_; d.K = HD_;
        d.W0 = W2xb; d.ldw0 = HD_; d.bias0 = b2x;
        d.N = HD_; d.nSplit = HD_; d.nValid = HD_;
        d.outB = phixNxt; d.ldo = HD_; d.epi = EPI_RELU_BF16; d.blockStart = bs; d.nTilesN = 32; bs += 128;
      }
      { GemmDesc& d = a.d[n++]; initD(d);
        d.epi = EPI_GRU; d.pf0 = gi; d.pf1 = gh; d.outF = h; d.outB = hbf;
        d.blockStart = bs; d.nTilesN = 64; bs += 64; }
      { GemmDesc& d = a.d[n++]; initD(d);
        d.epi = EPI_KLD; d.pf0 = pmps; d.pf1 = emes; d.red = out;
        d.blockStart = bs; d.nTilesN = 8; bs += 8; }
      a.n = n;
      k_gemm<64><<<bs, 256, 0, stream>>>(a);
    }
    { u16* tmp = phixCur; phixCur = phixNxt; phixNxt = tmp; }
  }
  // ---- final dm/NLL for t = T-1 ----
  {
    GemmArgs a; memset(&a, 0, sizeof(a));
    GemmDesc& d = a.d[0]; initD(d);
    d.A0 = dec_bf; d.lda0 = HD_; d.W0 = Wdmb; d.ldw0 = HD_; d.bias0 = bdm;
    d.N = 896; d.K = HD_; d.nSplit = 896; d.nValid = XD_;
    d.Af = x + (size_t)(T_ - 1) * B_ * XD_; d.red = out + 1;
    d.epi = EPI_NLL; d.blockStart = 0; d.nTilesN = 7;
    a.n = 1;
    k_gemm<128><<<28, 256, 0, stream>>>(a);
  }
}

// Round 4
// 13527.254 us; speedup vs baseline: 1.2653x; 1.2653x over previous
//
#include <hip/hip_runtime.h>
#include <stdint.h>
#include <string.h>

// ---------------- problem constants ----------------
#define T_ 64
#define B_ 256
#define XD_ 784
#define XDP_ 832   // XD padded to multiple of 64 for BK=64 staging
#define HD_ 2048
#define ZD_ 128
#define GD_ 6144   // 3*HD

typedef uint16_t u16;
typedef __attribute__((ext_vector_type(8))) short short8;
typedef __attribute__((ext_vector_type(4))) float floatx4;

enum { EPI_RELU_BF16 = 0, EPI_F32 = 1, EPI_ATOMF32 = 2, EPI_NLL = 3, EPI_GRU = 4, EPI_KLD = 5 };

struct GemmDesc {
  const u16* A0; const u16* A1; const float* Af;   // A1: concat-K second half; Af: f32 A (aF32) or x for NLL
  const u16* W0; const u16* W1;                    // W1: concat-N second half
  const float* bias0; const float* bias1;
  float* outF; u16* outB;
  const float* pf0; float* pf1; float* red;        // GRU: gi,gh ; KLD: pmps,emes ; red: atomic scalar
  int N, K, kSplit, nSplit, nValid;
  int lda0, lda1, ldw0, ldw1, ldo;
  int epi, aF32, blockStart, nTilesN;
};
struct GemmArgs { GemmDesc d[10]; int n; };

struct ConvSeg { const float* src; u16* dst; int dR, dC, sR, sC; };
struct ConvArgs {
  ConvSeg s[15]; int n;
  float* hz; long hzN;     // zero h (f32)
  float* zf; long zfN;     // zero emes (f32)
  u16* zb; long zbN;       // zero h_bf
  float* out2;             // zero outputs
};

// ---------------- device helpers ----------------
__device__ __forceinline__ u16 f2bf(float f) {
  union { float f; uint32_t u; } c; c.f = f;
  return (u16)((c.u + 0x7fffu + ((c.u >> 16) & 1u)) >> 16);   // RNE
}
__device__ __forceinline__ float spf(float x) { return fmaxf(x, 0.f) + log1pf(expf(-fabsf(x))); }
__device__ __forceinline__ float sigf(float x) { return 1.f / (1.f + expf(-x)); }

__device__ __forceinline__ void gl_lds16(const void* g, void* l) {
  // async global->LDS, 16B per lane; LDS dest is wave-uniform base + lane*16 (linear!)
  __builtin_amdgcn_global_load_lds((__attribute__((address_space(1))) void*)(uintptr_t)g,
                                   (__attribute__((address_space(3))) void*)(uintptr_t)l, 16, 0, 0);
}

// ---------------- weight/x conversion + zero-init (runs every call; ws is re-poisoned) ----------------
__global__ void k_convert(ConvArgs a) {
  const long gid = (long)blockIdx.x * blockDim.x + threadIdx.x;
  const long stride = (long)gridDim.x * blockDim.x;
  for (int s = 0; s < a.n; ++s) {
    ConvSeg g = a.s[s];
    const long tot = (long)g.dR * g.dC;
    if (g.sR == g.dR && g.sC == g.dC) {
      const long nv = tot >> 3;
      const floatx4* s4 = (const floatx4*)g.src;
      for (long i = gid; i < nv; i += stride) {
        floatx4 x0 = s4[2 * i], x1 = s4[2 * i + 1];
        short8 v;
        v[0] = (short)f2bf(x0[0]); v[1] = (short)f2bf(x0[1]); v[2] = (short)f2bf(x0[2]); v[3] = (short)f2bf(x0[3]);
        v[4] = (short)f2bf(x1[0]); v[5] = (short)f2bf(x1[1]); v[6] = (short)f2bf(x1[2]); v[7] = (short)f2bf(x1[3]);
        *(short8*)&g.dst[i * 8] = v;
      }
    } else {
      for (long i = gid; i < tot; i += stride) {
        const int r = (int)(i / g.dC), c = (int)(i - (long)r * g.dC);
        u16 v = 0;
        if (r < g.sR && c < g.sC) v = f2bf(g.src[(long)r * g.sC + c]);
        g.dst[i] = v;
      }
    }
  }
  for (long i = gid; i < a.hzN; i += stride) a.hz[i] = 0.f;
  for (long i = gid; i < a.zfN; i += stride) a.zf[i] = 0.f;
  for (long i = gid; i < a.zbN; i += stride) a.zb[i] = 0;
  if (gid == 0) { a.out2[0] = 0.f; a.out2[1] = 0.f; }
}

// ---------------- multi-descriptor GEMM: 64xBN tile, BK=64, double-buffered prefetch + XOR swizzle ----
// LDS layout: element (r,c) of a 64-col tile lives at elem index r*64 + (c ^ ((r&7)<<3)).
// global_load_lds writes linearly -> global source col is inverse-swizzled per lane (rule #21).
template <int BN>
__global__ __launch_bounds__(256)
void k_gemm(GemmArgs args) {
  __shared__ u16 smA[2][64 * 64];
  __shared__ u16 smB[2][BN * 64];
  __shared__ float rs[4];
  const int bid = blockIdx.x;
  int di = 0;
  while (di + 1 < args.n && bid >= args.d[di + 1].blockStart) ++di;
  const GemmDesc& d = args.d[di];
  const int tid = threadIdx.x, lane = tid & 63, wv = tid >> 6;

  if (d.epi == EPI_GRU) {   // elementwise GRU combine: h_new = (1-u)*n + u*h  (fp32 state)
    const int local = bid - d.blockStart;
    const long stride = (long)d.nTilesN * 256;
    for (long i = (long)local * 256 + tid; i < (long)B_ * HD_; i += stride) {
      const int m = (int)(i >> 11), j = (int)(i & (HD_ - 1));
      const float* gi = d.pf0 + (long)m * GD_;
      const float* gh = d.pf1 + (long)m * GD_;
      const float r = sigf(gi[j] + gh[j]);
      const float u = sigf(gi[HD_ + j] + gh[HD_ + j]);
      const float nn = tanhf(gi[2 * HD_ + j] + r * gh[2 * HD_ + j]);
      const float hv = d.outF[i];
      const float hn = (1.f - u) * nn + u * hv;
      d.outF[i] = hn;
      d.outB[i] = f2bf(hn);
    }
    return;
  }
  if (d.epi == EPI_KLD) {   // KL(enc||prior) over [B,ZD]; zero emes after read (next step's split-K atomics)
    const int local = bid - d.blockStart;
    const long stride = (long)d.nTilesN * 256;
    float sum = 0.f;
    for (long i = (long)local * 256 + tid; i < (long)B_ * ZD_; i += stride) {
      const int m = (int)(i >> 7), j = (int)(i & 127);
      const float* P = d.pf0 + m * 256;
      float* E = d.pf1 + m * 256;
      const float pm = P[j], psr = P[128 + j];
      const float em = E[j], esr = E[128 + j];
      const float ps = spf(psr), es = spf(esr);
      const float dmn = (em - pm) / ps, sr = es / ps;
      sum += dmn * dmn + sr * sr - 2.f * (logf(es) - logf(ps)) - 1.f;
      E[j] = 0.f; E[128 + j] = 0.f;
    }
    #pragma unroll
    for (int o = 32; o; o >>= 1) sum += __shfl_down(sum, o, 64);
    if (lane == 0) rs[wv] = sum;
    __syncthreads();
    if (tid == 0) atomicAdd(d.red, 0.5f * (rs[0] + rs[1] + rs[2] + rs[3]));
    return;
  }

  const int local = bid - d.blockStart;
  const int tm = local / d.nTilesN;
  const int tn = local - tm * d.nTilesN;
  const int mBase = tm * 64, nBase = tn * BN;

  const u16* Wr; const float* bias; int ldw; int bOff;
  if (nBase < d.nSplit) { Wr = d.W0 + (long)nBase * d.ldw0; ldw = d.ldw0; bias = d.bias0; bOff = nBase; }
  else { Wr = d.W1 + (long)(nBase - d.nSplit) * d.ldw1; ldw = d.ldw1; bias = d.bias1; bOff = nBase - d.nSplit; }

  const int wm = wv >> 1, wn = wv & 1;
  constexpr int FN = BN / 32;
  floatx4 acc[2][FN];
  #pragma unroll
  for (int a = 0; a < 2; ++a)
    #pragma unroll
    for (int b = 0; b < FN; ++b) acc[a][b] = (floatx4){0.f, 0.f, 0.f, 0.f};

  auto stageA = [&](int buf, int kk) {
    if (!d.aF32) {
      const u16* Ab; int lda;
      if (kk < d.kSplit) { Ab = d.A0 + kk; lda = d.lda0; }
      else { Ab = d.A1 + (kk - d.kSplit); lda = d.lda1; }
      #pragma unroll
      for (int it = 0; it < 2; ++it) {
        const int r = (it * 2048 + wv * 512 + lane * 8) >> 6;
        const int srcC = ((lane & 7) ^ (r & 7)) * 8;        // inverse swizzle on the global side
        gl_lds16(Ab + (long)(mBase + r) * lda + srcC, &smA[buf][it * 2048 + wv * 512]);
      }
    } else {   // fp32 A (x): load swizzled-source, convert, ds_write linear; zero-pad cols >= XD_
      #pragma unroll
      for (int it = 0; it < 2; ++it) {
        const int e = it * 2048 + wv * 512 + lane * 8;
        const int r = e >> 6;
        const int srcC = ((lane & 7) ^ (r & 7)) * 8;
        const int gm = mBase + r, cb = kk + srcC;
        float tv[8];
        if (cb + 8 <= XD_) {
          const floatx4* p = (const floatx4*)(d.Af + (long)gm * XD_ + cb);
          floatx4 a0 = p[0], a1 = p[1];
          tv[0] = a0[0]; tv[1] = a0[1]; tv[2] = a0[2]; tv[3] = a0[3];
          tv[4] = a1[0]; tv[5] = a1[1]; tv[6] = a1[2]; tv[7] = a1[3];
        } else {
          #pragma unroll
          for (int j = 0; j < 8; ++j) tv[j] = (cb + j < XD_) ? d.Af[(long)gm * XD_ + cb + j] : 0.f;
        }
        short8 v;
        #pragma unroll
        for (int j = 0; j < 8; ++j) v[j] = (short)f2bf(tv[j]);
        *(short8*)&smA[buf][e] = v;
      }
    }
  };
  auto stageB = [&](int buf, int kk) {
    #pragma unroll
    for (int it = 0; it < FN; ++it) {
      const int r = (it * 2048 + wv * 512 + lane * 8) >> 6;
      const int srcC = ((lane & 7) ^ (r & 7)) * 8;
      gl_lds16(Wr + (long)r * ldw + kk + srcC, &smB[buf][it * 2048 + wv * 512]);
    }
  };
  auto compute = [&](int buf) {
    #pragma unroll
    for (int ks = 0; ks < 2; ++ks) {
      const int ko = ks * 32 + (lane >> 4) * 8;
      const int ra0 = wm * 32 + (lane & 15);
      const int ra1 = ra0 + 16;
      short8 af0 = *(const short8*)&smA[buf][ra0 * 64 + (ko ^ ((ra0 & 7) << 3))];
      short8 af1 = *(const short8*)&smA[buf][ra1 * 64 + (ko ^ ((ra1 & 7) << 3))];
      #pragma unroll
      for (int fn = 0; fn < FN; ++fn) {
        const int rb = wn * (BN / 2) + fn * 16 + (lane & 15);
        short8 bf = *(const short8*)&smB[buf][rb * 64 + (ko ^ ((rb & 7) << 3))];
        acc[0][fn] = __builtin_amdgcn_mfma_f32_16x16x32_bf16(af0, bf, acc[0][fn], 0, 0, 0);
        acc[1][fn] = __builtin_amdgcn_mfma_f32_16x16x32_bf16(af1, bf, acc[1][fn], 0, 0, 0);
      }
    }
  };

  const int nkt = d.K >> 6;
  stageA(0, 0); stageB(0, 0);
  __syncthreads();
  for (int kt = 0; kt < nkt; ++kt) {
    const int cur = kt & 1;
    if (kt + 1 < nkt) { stageA(cur ^ 1, (kt + 1) << 6); stageB(cur ^ 1, (kt + 1) << 6); }
    compute(cur);
    __syncthreads();   // drains prefetch (had full compute phase to land) + protects buffer reuse
  }

  // epilogue: C/D layout col=lane&15, row=(lane>>4)*4+reg
  float nllSum = 0.f;
  #pragma unroll
  for (int fm = 0; fm < 2; ++fm)
    #pragma unroll
    for (int fn = 0; fn < FN; ++fn)
      #pragma unroll
      for (int j = 0; j < 4; ++j) {
        const int row = wm * 32 + fm * 16 + (lane >> 4) * 4 + j;
        const int col = wn * (BN / 2) + fn * 16 + (lane & 15);
        const int gm = mBase + row, gn = nBase + col;
        if (gn >= d.nValid) continue;
        float v = acc[fm][fn][j];
        if (bias) v += bias[bOff + col];
        switch (d.epi) {
          case EPI_RELU_BF16: d.outB[(long)gm * d.ldo + gn] = f2bf(fmaxf(v, 0.f)); break;
          case EPI_F32:       d.outF[(long)gm * d.ldo + gn] = v; break;
          case EPI_ATOMF32:   atomicAdd(&d.outF[(long)gm * d.ldo + gn], v); break;
          case EPI_NLL: {
            // dm = sigmoid(v); clip(log dm,-100) = -min(sp(-v),100); clip(log1p(-dm),-100) = -min(sp(v),100)
            const float xv = d.Af[(long)gm * XD_ + gn];
            nllSum += xv * fminf(spf(-v), 100.f) + (1.f - xv) * fminf(spf(v), 100.f);
          } break;
        }
      }
  if (d.epi == EPI_NLL) {
    #pragma unroll
    for (int o = 32; o; o >>= 1) nllSum += __shfl_down(nllSum, o, 64);
    if (lane == 0) rs[wv] = nllSum;
    __syncthreads();
    if (tid == 0) atomicAdd(d.red, rs[0] + rs[1] + rs[2] + rs[3]);
  }
}

// ---------------- fused z = eps*softplus(es)+em  ->  phi_z = relu(z@Wzp^T+bzp)  (K=128, 64x64 tiles) ----
// 128-col LDS tiles: element (r,c) at idx r*128 + (c ^ ((r&15)<<3)).
__global__ __launch_bounds__(256)
void k_phiz(const float* emes, const float* eps_t, const u16* Wzp, const float* bzp, u16* phiz) {
  __shared__ u16 zA[64 * 128];
  __shared__ u16 wB[64 * 128];
  const int bid = blockIdx.x;
  const int tm = bid >> 5, tn = bid & 31;
  const int mBase = tm * 64, nBase = tn * 64;
  const int tid = threadIdx.x, lane = tid & 63, wv = tid >> 6;
  #pragma unroll
  for (int it = 0; it < 4; ++it) {
    const int e = it * 2048 + wv * 512 + lane * 8;
    const int r = e >> 7;
    const int s = (e & 127) >> 3;
    const int srcC = (s ^ (r & 15)) * 8;
    gl_lds16(Wzp + (long)(nBase + r) * 128 + srcC, &wB[it * 2048 + wv * 512]);
  }
  for (int i = tid; i < 64 * 16; i += 256) {
    const int m = i >> 4, j0 = (i & 15) * 8;
    const int gm = mBase + m;
    const floatx4* pe = (const floatx4*)(emes + gm * 256 + j0);
    const floatx4* pv = (const floatx4*)(emes + gm * 256 + 128 + j0);
    const floatx4* pp = (const floatx4*)(eps_t + (long)gm * 128 + j0);
    floatx4 em0 = pe[0], em1 = pe[1], es0 = pv[0], es1 = pv[1], ep0 = pp[0], ep1 = pp[1];
    short8 v;
    #pragma unroll
    for (int j = 0; j < 4; ++j) v[j] = (short)f2bf(ep0[j] * spf(es0[j]) + em0[j]);
    #pragma unroll
    for (int j = 0; j < 4; ++j) v[4 + j] = (short)f2bf(ep1[j] * spf(es1[j]) + em1[j]);
    *(short8*)&zA[m * 128 + (j0 ^ ((m & 15) << 3))] = v;
  }
  __syncthreads();
  const int wm = wv >> 1, wn = wv & 1;
  floatx4 acc[2][2];
  #pragma unroll
  for (int a = 0; a < 2; ++a)
    #pragma unroll
    for (int b = 0; b < 2; ++b) acc[a][b] = (floatx4){0.f, 0.f, 0.f, 0.f};
  #pragma unroll
  for (int ks = 0; ks < 4; ++ks) {
    const int ko = ks * 32 + (lane >> 4) * 8;
    const int ra0 = wm * 32 + (lane & 15), ra1 = ra0 + 16;
    short8 a0 = *(const short8*)&zA[ra0 * 128 + (ko ^ ((ra0 & 15) << 3))];
    short8 a1 = *(const short8*)&zA[ra1 * 128 + (ko ^ ((ra1 & 15) << 3))];
    #pragma unroll
    for (int fn = 0; fn < 2; ++fn) {
      const int rb = wn * 32 + fn * 16 + (lane & 15);
      short8 bf = *(const short8*)&wB[rb * 128 + (ko ^ ((rb & 15) << 3))];
      acc[0][fn] = __builtin_amdgcn_mfma_f32_16x16x32_bf16(a0, bf, acc[0][fn], 0, 0, 0);
      acc[1][fn] = __builtin_amdgcn_mfma_f32_16x16x32_bf16(a1, bf, acc[1][fn], 0, 0, 0);
    }
  }
  #pragma unroll
  for (int fm = 0; fm < 2; ++fm)
    #pragma unroll
    for (int fn = 0; fn < 2; ++fn)
      #pragma unroll
      for (int j = 0; j < 4; ++j) {
        const int row = wm * 32 + fm * 16 + (lane >> 4) * 4 + j;
        const int col = wn * 32 + fn * 16 + (lane & 15);
        phiz[(long)(mBase + row) * HD_ + nBase + col] = f2bf(fmaxf(acc[fm][fn][j] + bzp[nBase + col], 0.f));
      }
}

// ---------------- host ----------------
extern "C" void kernel_launch(void* const* d_in, const int* in_sizes, int n_in,
                              void* d_out, int out_size, void* d_ws, size_t ws_size,
                              hipStream_t stream) {
  const float* x   = (const float*)d_in[0];
  const float* eps = (const float*)d_in[1];
  const float* W1x = (const float*)d_in[2];  const float* b1x = (const float*)d_in[3];
  const float* W2x = (const float*)d_in[4];  const float* b2x = (const float*)d_in[5];
  const float* Wzp = (const float*)d_in[6];  const float* bzp = (const float*)d_in[7];
  const float* Wpr = (const float*)d_in[8];  const float* bpr = (const float*)d_in[9];
  const float* Wpm = (const float*)d_in[10]; const float* bpm = (const float*)d_in[11];
  const float* Wps = (const float*)d_in[12]; const float* bps = (const float*)d_in[13];
  const float* We1 = (const float*)d_in[14]; const float* be1 = (const float*)d_in[15];
  const float* We2 = (const float*)d_in[16]; const float* be2 = (const float*)d_in[17];
  const float* Wem = (const float*)d_in[18]; const float* bem = (const float*)d_in[19];
  const float* Wes = (const float*)d_in[20]; const float* bes = (const float*)d_in[21];
  const float* Wd1 = (const float*)d_in[22]; const float* bd1 = (const float*)d_in[23];
  const float* Wd2 = (const float*)d_in[24]; const float* bd2 = (const float*)d_in[25];
  const float* Wdm = (const float*)d_in[26]; const float* bdm = (const float*)d_in[27];
  const float* Wih = (const float*)d_in[28]; const float* bih = (const float*)d_in[29];
  const float* Whh = (const float*)d_in[30]; const float* bhh = (const float*)d_in[31];
  float* out = (float*)d_out;

  char* base = (char*)d_ws; size_t off = 0;
  auto alc = [&](size_t bytes) -> void* {
    void* r = base + off; off = (off + bytes + 255) & ~(size_t)255; return r;
  };
  // bf16 weights
  u16* W1xb = (u16*)alc((size_t)2048 * XDP_ * 2);
  u16* W2xb = (u16*)alc((size_t)2048 * 2048 * 2);
  u16* Wzpb = (u16*)alc((size_t)2048 * 128 * 2);
  u16* Wprb = (u16*)alc((size_t)2048 * 2048 * 2);
  u16* Wpmb = (u16*)alc((size_t)128 * 2048 * 2);
  u16* Wpsb = (u16*)alc((size_t)128 * 2048 * 2);
  u16* We1b = (u16*)alc((size_t)2048 * 4096 * 2);
  u16* We2b = (u16*)alc((size_t)2048 * 2048 * 2);
  u16* Wemb = (u16*)alc((size_t)128 * 2048 * 2);
  u16* Wesb = (u16*)alc((size_t)128 * 2048 * 2);
  u16* Wd1b = (u16*)alc((size_t)2048 * 4096 * 2);
  u16* Wd2b = (u16*)alc((size_t)2048 * 2048 * 2);
  u16* Wdmb = (u16*)alc((size_t)896 * 2048 * 2);   // N-padded 784->896, pad rows zero
  u16* Wihb = (u16*)alc((size_t)6144 * 4096 * 2);
  u16* Whhb = (u16*)alc((size_t)6144 * 2048 * 2);
  // activations
  u16* phixA   = (u16*)alc((size_t)B_ * HD_ * 2);
  u16* phixB   = (u16*)alc((size_t)B_ * HD_ * 2);
  u16* ph1     = (u16*)alc((size_t)B_ * HD_ * 2);
  float* h     = (float*)alc((size_t)B_ * HD_ * 4);
  u16* hbf     = (u16*)alc((size_t)B_ * HD_ * 2);
  u16* prior_bf= (u16*)alc((size_t)B_ * HD_ * 2);
  u16* enc1_bf = (u16*)alc((size_t)B_ * HD_ * 2);
  u16* enc_bf  = (u16*)alc((size_t)B_ * HD_ * 2);
  u16* dec1_bf = (u16*)alc((size_t)B_ * HD_ * 2);
  u16* dec_bf  = (u16*)alc((size_t)B_ * HD_ * 2);
  u16* phiz_bf = (u16*)alc((size_t)B_ * HD_ * 2);
  float* pmps  = (float*)alc((size_t)B_ * 256 * 4);
  float* emes  = (float*)alc((size_t)B_ * 256 * 4);
  float* gi    = (float*)alc((size_t)B_ * GD_ * 4);
  float* gh    = (float*)alc((size_t)B_ * GD_ * 4);
  if (off > ws_size) return;   // workspace too small -> loud validation failure, not corruption

  // ---- convert weights to bf16, zero h/h_bf/emes/out ----
  {
    ConvArgs ca; memset(&ca, 0, sizeof(ca));
    int ns = 0;
    auto seg = [&](const float* s, u16* dst, int dR, int dC, int sR, int sC) {
      ca.s[ns].src = s; ca.s[ns].dst = dst; ca.s[ns].dR = dR; ca.s[ns].dC = dC; ca.s[ns].sR = sR; ca.s[ns].sC = sC; ++ns;
    };
    seg(W1x, W1xb, 2048, XDP_, 2048, XD_);
    seg(W2x, W2xb, 2048, 2048, 2048, 2048);
    seg(Wzp, Wzpb, 2048, 128, 2048, 128);
    seg(Wpr, Wprb, 2048, 2048, 2048, 2048);
    seg(Wpm, Wpmb, 128, 2048, 128, 2048);
    seg(Wps, Wpsb, 128, 2048, 128, 2048);
    seg(We1, We1b, 2048, 4096, 2048, 4096);
    seg(We2, We2b, 2048, 2048, 2048, 2048);
    seg(Wem, Wemb, 128, 2048, 128, 2048);
    seg(Wes, Wesb, 128, 2048, 128, 2048);
    seg(Wd1, Wd1b, 2048, 4096, 2048, 4096);
    seg(Wd2, Wd2b, 2048, 2048, 2048, 2048);
    seg(Wdm, Wdmb, 896, 2048, 784, 2048);
    seg(Wih, Wihb, 6144, 4096, 6144, 4096);
    seg(Whh, Whhb, 6144, 2048, 6144, 2048);
    ca.n = ns;
    ca.hz = h;   ca.hzN = (long)B_ * HD_;
    ca.zf = emes; ca.zfN = (long)B_ * 256;
    ca.zb = hbf; ca.zbN = (long)B_ * HD_;
    ca.out2 = out;
    k_convert<<<1024, 256, 0, stream>>>(ca);
  }

  auto initD = [](GemmDesc& d) { memset(&d, 0, sizeof(d)); d.kSplit = 1 << 30; };

  // ---- prologue: phi_x(0) ----
  {
    GemmArgs a; memset(&a, 0, sizeof(a));
    GemmDesc& d = a.d[0]; initD(d);
    d.aF32 = 1; d.Af = x; d.K = XDP_;
    d.W0 = W1xb; d.ldw0 = XDP_; d.bias0 = b1x;
    d.N = HD_; d.nSplit = HD_; d.nValid = HD_;
    d.outB = ph1; d.ldo = HD_; d.epi = EPI_RELU_BF16; d.blockStart = 0; d.nTilesN = 32;
    a.n = 1;
    k_gemm<64><<<128, 256, 0, stream>>>(a);
  }
  {
    GemmArgs a; memset(&a, 0, sizeof(a));
    GemmDesc& d = a.d[0]; initD(d);
    d.A0 = ph1; d.lda0 = HD_; d.K = HD_;
    d.W0 = W2xb; d.ldw0 = HD_; d.bias0 = b2x;
    d.N = HD_; d.nSplit = HD_; d.nValid = HD_;
    d.outB = phixA; d.ldo = HD_; d.epi = EPI_RELU_BF16; d.blockStart = 0; d.nTilesN = 32;
    a.n = 1;
    k_gemm<64><<<128, 256, 0, stream>>>(a);
  }

  u16* phixCur = phixA; u16* phixNxt = phixB;
  for (int t = 0; t < T_; ++t) {
    // ---- S1: prior, enc1, gh ----
    {
      GemmArgs a; memset(&a, 0, sizeof(a));
      int bs = 0, n = 0;
      { GemmDesc& d = a.d[n++]; initD(d);
        d.A0 = hbf; d.lda0 = HD_; d.W0 = Wprb; d.ldw0 = HD_; d.bias0 = bpr;
        d.N = HD_; d.K = HD_; d.nSplit = HD_; d.nValid = HD_;
        d.outB = prior_bf; d.ldo = HD_; d.epi = EPI_RELU_BF16; d.blockStart = bs; d.nTilesN = 16; bs += 64; }
      { GemmDesc& d = a.d[n++]; initD(d);
        d.A0 = phixCur; d.lda0 = HD_; d.A1 = hbf; d.lda1 = HD_; d.kSplit = HD_;
        d.W0 = We1b; d.ldw0 = 4096; d.bias0 = be1;
        d.N = HD_; d.K = 4096; d.nSplit = HD_; d.nValid = HD_;
        d.outB = enc1_bf; d.ldo = HD_; d.epi = EPI_RELU_BF16; d.blockStart = bs; d.nTilesN = 16; bs += 64; }
      { GemmDesc& d = a.d[n++]; initD(d);
        d.A0 = hbf; d.lda0 = HD_; d.W0 = Whhb; d.ldw0 = HD_; d.bias0 = bhh;
        d.N = GD_; d.K = HD_; d.nSplit = GD_; d.nValid = GD_;
        d.outF = gh; d.ldo = GD_; d.epi = EPI_F32; d.blockStart = bs; d.nTilesN = 48; bs += 192; }
      a.n = n;
      k_gemm<128><<<bs, 256, 0, stream>>>(a);
    }
    // ---- S2: enc2, pm/ps ----
    {
      GemmArgs a; memset(&a, 0, sizeof(a));
      int bs = 0, n = 0;
      { GemmDesc& d = a.d[n++]; initD(d);
        d.A0 = enc1_bf; d.lda0 = HD_; d.W0 = We2b; d.ldw0 = HD_; d.bias0 = be2;
        d.N = HD_; d.K = HD_; d.nSplit = HD_; d.nValid = HD_;
        d.outB = enc_bf; d.ldo = HD_; d.epi = EPI_RELU_BF16; d.blockStart = bs; d.nTilesN = 32; bs += 128; }
      { GemmDesc& d = a.d[n++]; initD(d);
        d.A0 = prior_bf; d.lda0 = HD_;
        d.W0 = Wpmb; d.ldw0 = HD_; d.W1 = Wpsb; d.ldw1 = HD_; d.bias0 = bpm; d.bias1 = bps;
        d.N = 256; d.K = HD_; d.nSplit = 128; d.nValid = 256;
        d.outF = pmps; d.ldo = 256; d.epi = EPI_F32; d.blockStart = bs; d.nTilesN = 4; bs += 16; }
      a.n = n;
      k_gemm<64><<<bs, 256, 0, stream>>>(a);
    }
    // ---- S3: em/es (split-K x8, atomic into zeroed emes) + NLL of step t-1 ----
    {
      GemmArgs a; memset(&a, 0, sizeof(a));
      int bs = 0, n = 0;
      for (int c = 0; c < 8; ++c) {
        GemmDesc& d = a.d[n++]; initD(d);
        d.A0 = enc_bf + c * 256; d.lda0 = HD_;
        d.W0 = Wemb + c * 256; d.ldw0 = HD_; d.W1 = Wesb + c * 256; d.ldw1 = HD_;
        d.bias0 = (c == 0) ? bem : nullptr; d.bias1 = (c == 0) ? bes : nullptr;
        d.N = 256; d.K = 256; d.nSplit = 128; d.nValid = 256;
        d.outF = emes; d.ldo = 256; d.epi = EPI_ATOMF32; d.blockStart = bs; d.nTilesN = 4; bs += 16;
      }
      if (t > 0) {
        GemmDesc& d = a.d[n++]; initD(d);
        d.A0 = dec_bf; d.lda0 = HD_; d.W0 = Wdmb; d.ldw0 = HD_; d.bias0 = bdm;
        d.N = 896; d.K = HD_; d.nSplit = 896; d.nValid = XD_;
        d.Af = x + (size_t)(t - 1) * B_ * XD_; d.red = out + 1;
        d.epi = EPI_NLL; d.blockStart = bs; d.nTilesN = 14; bs += 56;
      }
      a.n = n;
      k_gemm<64><<<bs, 256, 0, stream>>>(a);
    }
    // ---- S4: z + phi_z ----
    k_phiz<<<128, 256, 0, stream>>>(emes, eps + (size_t)t * B_ * ZD_, Wzpb, bzp, phiz_bf);
    // ---- S5: dec1, gi  (+ phi_x stage1 for t+1) ----
    {
      GemmArgs a; memset(&a, 0, sizeof(a));
      int bs = 0, n = 0;
      { GemmDesc& d = a.d[n++]; initD(d);
        d.A0 = phiz_bf; d.lda0 = HD_; d.A1 = hbf; d.lda1 = HD_; d.kSplit = HD_;
        d.W0 = Wd1b; d.ldw0 = 4096; d.bias0 = bd1;
        d.N = HD_; d.K = 4096; d.nSplit = HD_; d.nValid = HD_;
        d.outB = dec1_bf; d.ldo = HD_; d.epi = EPI_RELU_BF16; d.blockStart = bs; d.nTilesN = 16; bs += 64; }
      { GemmDesc& d = a.d[n++]; initD(d);
        d.A0 = phixCur; d.lda0 = HD_; d.A1 = phiz_bf; d.lda1 = HD_; d.kSplit = HD_;
        d.W0 = Wihb; d.ldw0 = 4096; d.bias0 = bih;
        d.N = GD_; d.K = 4096; d.nSplit = GD_; d.nValid = GD_;
        d.outF = gi; d.ldo = GD_; d.epi = EPI_F32; d.blockStart = bs; d.nTilesN = 48; bs += 192; }
      if (t < T_ - 1) {
        GemmDesc& d = a.d[n++]; initD(d);
        d.aF32 = 1; d.Af = x + (size_t)(t + 1) * B_ * XD_; d.K = XDP_;
        d.W0 = W1xb; d.ldw0 = XDP_; d.bias0 = b1x;
        d.N = HD_; d.nSplit = HD_; d.nValid = HD_;
        d.outB = ph1; d.ldo = HD_; d.epi = EPI_RELU_BF16; d.blockStart = bs; d.nTilesN = 16; bs += 64;
      }
      a.n = n;
      k_gemm<128><<<bs, 256, 0, stream>>>(a);
    }
    // ---- S6: dec2, phi_x stage2 (t+1), GRU combine, KLD ----
    {
      GemmArgs a; memset(&a, 0, sizeof(a));
      int bs = 0, n = 0;
      { GemmDesc& d = a.d[n++]; initD(d);
        d.A0 = dec1_bf; d.lda0 = HD_; d.W0 = Wd2b; d.ldw0 = HD_; d.bias0 = bd2;
        d.N = HD_; d.K = HD_; d.nSplit = HD_; d.nValid = HD_;
        d.outB = dec_bf; d.ldo = HD_; d.epi = EPI_RELU_BF16; d.blockStart = bs; d.nTilesN = 32; bs += 128; }
      if (t < T_ - 1) {
        GemmDesc& d = a.d[n++]; initD(d);
        d.A0 = ph1; d.lda0 = HD_; d.K = HD_;
        d.W0 = W2xb; d.ldw0 = HD_; d.bias0 = b2x;
        d.N = HD_; d.nSplit = HD_; d.nValid = HD_;
        d.outB = phixNxt; d.ldo = HD_; d.epi = EPI_RELU_BF16; d.blockStart = bs; d.nTilesN = 32; bs += 128;
      }
      { GemmDesc& d = a.d[n++]; initD(d);
        d.epi = EPI_GRU; d.pf0 = gi; d.pf1 = gh; d.outF = h; d.outB = hbf;
        d.blockStart = bs; d.nTilesN = 64; bs += 64; }
      { GemmDesc& d = a.d[n++]; initD(d);
        d.epi = EPI_KLD; d.pf0 = pmps; d.pf1 = emes; d.red = out;
        d.blockStart = bs; d.nTilesN = 8; bs += 8; }
      a.n = n;
      k_gemm<64><<<bs, 256, 0, stream>>>(a);
    }
    { u16* tmp = phixCur; phixCur = phixNxt; phixNxt = tmp; }
  }
  // ---- final dm/NLL for t = T-1 ----
  {
    GemmArgs a; memset(&a, 0, sizeof(a));
    GemmDesc& d = a.d[0]; initD(d);
    d.A0 = dec_bf; d.lda0 = HD_; d.W0 = Wdmb; d.ldw0 = HD_; d.bias0 = bdm;
    d.N = 896; d.K = HD_; d.nSplit = 896; d.nValid = XD_;
    d.Af = x + (size_t)(T_ - 1) * B_ * XD_; d.red = out + 1;
    d.epi = EPI_NLL; d.blockStart = 0; d.nTilesN = 14;
    a.n = 1;
    k_gemm<64><<<56, 256, 0, stream>>>(a);
  }
}

// Round 6
// 12234.480 us; speedup vs baseline: 1.3990x; 1.1057x over previous
//
#include <hip/hip_runtime.h>
#include <stdint.h>
#include <string.h>

// ---------------- problem constants ----------------
#define T_ 64
#define B_ 256
#define XD_ 784
#define XDP_ 832   // XD padded to multiple of 64 for BK=64 staging
#define HD_ 2048
#define ZD_ 128
#define GD_ 6144   // 3*HD

typedef uint16_t u16;
typedef __attribute__((ext_vector_type(8))) short short8;
typedef __attribute__((ext_vector_type(4))) float floatx4;

enum { EPI_RELU_BF16 = 0, EPI_F32 = 1, EPI_ATOMF32 = 2, EPI_NLL = 3, EPI_GRU = 4, EPI_KLD = 5 };

struct GemmDesc {
  const u16* A0; const u16* A1; const float* Af;   // A1: concat-K second half; Af: f32 A (aF32) or x for NLL
  const u16* W0; const u16* W1;                    // W1: concat-N second half
  const float* bias0; const float* bias1;
  float* outF; u16* outB;
  const float* pf0; float* pf1; float* red;        // GRU: gi,gh ; KLD: pmps,emes ; red: atomic scalar
  int N, K, kSplit, nSplit, nValid;
  int lda0, lda1, ldw0, ldw1, ldo;
  int epi, aF32, blockStart, nTilesN;
};
struct GemmArgs { GemmDesc d[10]; int n; };

struct ConvSeg { const float* src; u16* dst; int dR, dC, sR, sC; };
struct ConvArgs {
  ConvSeg s[15]; int n;
  float* hz; long hzN;     // zero h (f32)
  float* zf; long zfN;     // zero emes (f32)
  u16* zb; long zbN;       // zero h_bf
  float* out2;             // zero outputs
};

// ---------------- device helpers ----------------
__device__ __forceinline__ u16 f2bf(float f) {
  union { float f; uint32_t u; } c; c.f = f;
  return (u16)((c.u + 0x7fffu + ((c.u >> 16) & 1u)) >> 16);   // RNE
}
__device__ __forceinline__ float spf(float x) { return fmaxf(x, 0.f) + log1pf(expf(-fabsf(x))); }
__device__ __forceinline__ float sigf(float x) { return 1.f / (1.f + expf(-x)); }

__device__ __forceinline__ void gl_lds16(const void* g, void* l) {
  // async global->LDS, 16B per lane; LDS dest is wave-uniform base + lane*16 (linear!)
  __builtin_amdgcn_global_load_lds((__attribute__((address_space(1))) void*)(uintptr_t)g,
                                   (__attribute__((address_space(3))) void*)(uintptr_t)l, 16, 0, 0);
}

// ---------------- weight/x conversion + zero-init (runs every call; ws is re-poisoned) ----------------
__global__ void k_convert(ConvArgs a) {
  const long gid = (long)blockIdx.x * blockDim.x + threadIdx.x;
  const long stride = (long)gridDim.x * blockDim.x;
  for (int s = 0; s < a.n; ++s) {
    ConvSeg g = a.s[s];
    const long tot = (long)g.dR * g.dC;
    if (g.sR == g.dR && g.sC == g.dC) {
      const long nv = tot >> 3;
      const floatx4* s4 = (const floatx4*)g.src;
      for (long i = gid; i < nv; i += stride) {
        floatx4 x0 = s4[2 * i], x1 = s4[2 * i + 1];
        short8 v;
        v[0] = (short)f2bf(x0[0]); v[1] = (short)f2bf(x0[1]); v[2] = (short)f2bf(x0[2]); v[3] = (short)f2bf(x0[3]);
        v[4] = (short)f2bf(x1[0]); v[5] = (short)f2bf(x1[1]); v[6] = (short)f2bf(x1[2]); v[7] = (short)f2bf(x1[3]);
        *(short8*)&g.dst[i * 8] = v;
      }
    } else {
      for (long i = gid; i < tot; i += stride) {
        const int r = (int)(i / g.dC), c = (int)(i - (long)r * g.dC);
        u16 v = 0;
        if (r < g.sR && c < g.sC) v = f2bf(g.src[(long)r * g.sC + c]);
        g.dst[i] = v;
      }
    }
  }
  for (long i = gid; i < a.hzN; i += stride) a.hz[i] = 0.f;
  for (long i = gid; i < a.zfN; i += stride) a.zf[i] = 0.f;
  for (long i = gid; i < a.zbN; i += stride) a.zb[i] = 0;
  if (gid == 0) { a.out2[0] = 0.f; a.out2[1] = 0.f; }
}

// ---------------- multi-descriptor GEMM: 64x64 tile, BK=64, double-buffered prefetch + XOR swizzle ----
// LDS layout: element (r,c) of a 64-col tile lives at elem index r*64 + (c ^ ((r&7)<<3)).
// global_load_lds writes linearly -> global source col is inverse-swizzled per lane (rule #21).
// __launch_bounds__(256,2): 2 waves/EU -> 2 blocks/CU co-residency (the TLP that hides L3 latency).
__global__ __launch_bounds__(256, 2)
void k_gemm(GemmArgs args) {
  constexpr int BN = 64;
  __shared__ u16 smA[2][64 * 64];
  __shared__ u16 smB[2][BN * 64];
  __shared__ float rs[4];
  const int bid = blockIdx.x;
  int di = 0;
  while (di + 1 < args.n && bid >= args.d[di + 1].blockStart) ++di;
  const GemmDesc& d = args.d[di];
  const int tid = threadIdx.x, lane = tid & 63, wv = tid >> 6;

  if (d.epi == EPI_GRU) {   // elementwise GRU combine: h_new = (1-u)*n + u*h  (fp32 state)
    const int local = bid - d.blockStart;
    const long stride = (long)d.nTilesN * 256;
    for (long i = (long)local * 256 + tid; i < (long)B_ * HD_; i += stride) {
      const int m = (int)(i >> 11), j = (int)(i & (HD_ - 1));
      const float* gi = d.pf0 + (long)m * GD_;
      const float* gh = d.pf1 + (long)m * GD_;
      const float r = sigf(gi[j] + gh[j]);
      const float u = sigf(gi[HD_ + j] + gh[HD_ + j]);
      const float nn = tanhf(gi[2 * HD_ + j] + r * gh[2 * HD_ + j]);
      const float hv = d.outF[i];
      const float hn = (1.f - u) * nn + u * hv;
      d.outF[i] = hn;
      d.outB[i] = f2bf(hn);
    }
    return;
  }
  if (d.epi == EPI_KLD) {   // KL(enc||prior) over [B,ZD]; zero emes after read (next step's split-K atomics)
    const int local = bid - d.blockStart;
    const long stride = (long)d.nTilesN * 256;
    float sum = 0.f;
    for (long i = (long)local * 256 + tid; i < (long)B_ * ZD_; i += stride) {
      const int m = (int)(i >> 7), j = (int)(i & 127);
      const float* P = d.pf0 + m * 256;
      float* E = d.pf1 + m * 256;
      const float pm = P[j], psr = P[128 + j];
      const float em = E[j], esr = E[128 + j];
      const float ps = spf(psr), es = spf(esr);
      const float dmn = (em - pm) / ps, sr = es / ps;
      sum += dmn * dmn + sr * sr - 2.f * (logf(es) - logf(ps)) - 1.f;
      E[j] = 0.f; E[128 + j] = 0.f;
    }
    #pragma unroll
    for (int o = 32; o; o >>= 1) sum += __shfl_down(sum, o, 64);
    if (lane == 0) rs[wv] = sum;
    __syncthreads();
    if (tid == 0) atomicAdd(d.red, 0.5f * (rs[0] + rs[1] + rs[2] + rs[3]));
    return;
  }

  const int local = bid - d.blockStart;
  const int tm = local / d.nTilesN;
  const int tn = local - tm * d.nTilesN;
  const int mBase = tm * 64, nBase = tn * BN;

  const u16* Wr; const float* bias; int ldw; int bOff;
  if (nBase < d.nSplit) { Wr = d.W0 + (long)nBase * d.ldw0; ldw = d.ldw0; bias = d.bias0; bOff = nBase; }
  else { Wr = d.W1 + (long)(nBase - d.nSplit) * d.ldw1; ldw = d.ldw1; bias = d.bias1; bOff = nBase - d.nSplit; }

  const int wm = wv >> 1, wn = wv & 1;
  constexpr int FN = BN / 32;
  floatx4 acc[2][FN];
  #pragma unroll
  for (int a = 0; a < 2; ++a)
    #pragma unroll
    for (int b = 0; b < FN; ++b) acc[a][b] = (floatx4){0.f, 0.f, 0.f, 0.f};

  auto stageA = [&](int buf, int kk) {
    if (!d.aF32) {
      const u16* Ab; int lda;
      if (kk < d.kSplit) { Ab = d.A0 + kk; lda = d.lda0; }
      else { Ab = d.A1 + (kk - d.kSplit); lda = d.lda1; }
      #pragma unroll
      for (int it = 0; it < 2; ++it) {
        const int r = (it * 2048 + wv * 512 + lane * 8) >> 6;
        const int srcC = ((lane & 7) ^ (r & 7)) * 8;        // inverse swizzle on the global side
        gl_lds16(Ab + (long)(mBase + r) * lda + srcC, &smA[buf][it * 2048 + wv * 512]);
      }
    } else {   // fp32 A (x): load swizzled-source, convert, ds_write linear; zero-pad cols >= XD_
      #pragma unroll
      for (int it = 0; it < 2; ++it) {
        const int e = it * 2048 + wv * 512 + lane * 8;
        const int r = e >> 6;
        const int srcC = ((lane & 7) ^ (r & 7)) * 8;
        const int gm = mBase + r, cb = kk + srcC;
        float tv[8];
        if (cb + 8 <= XD_) {
          const floatx4* p = (const floatx4*)(d.Af + (long)gm * XD_ + cb);
          floatx4 a0 = p[0], a1 = p[1];
          tv[0] = a0[0]; tv[1] = a0[1]; tv[2] = a0[2]; tv[3] = a0[3];
          tv[4] = a1[0]; tv[5] = a1[1]; tv[6] = a1[2]; tv[7] = a1[3];
        } else {
          #pragma unroll
          for (int j = 0; j < 8; ++j) tv[j] = (cb + j < XD_) ? d.Af[(long)gm * XD_ + cb + j] : 0.f;
        }
        short8 v;
        #pragma unroll
        for (int j = 0; j < 8; ++j) v[j] = (short)f2bf(tv[j]);
        *(short8*)&smA[buf][e] = v;
      }
    }
  };
  auto stageB = [&](int buf, int kk) {
    #pragma unroll
    for (int it = 0; it < FN; ++it) {
      const int r = (it * 2048 + wv * 512 + lane * 8) >> 6;
      const int srcC = ((lane & 7) ^ (r & 7)) * 8;
      gl_lds16(Wr + (long)r * ldw + kk + srcC, &smB[buf][it * 2048 + wv * 512]);
    }
  };
  auto compute = [&](int buf) {
    #pragma unroll
    for (int ks = 0; ks < 2; ++ks) {
      const int ko = ks * 32 + (lane >> 4) * 8;
      const int ra0 = wm * 32 + (lane & 15);
      const int ra1 = ra0 + 16;
      short8 af0 = *(const short8*)&smA[buf][ra0 * 64 + (ko ^ ((ra0 & 7) << 3))];
      short8 af1 = *(const short8*)&smA[buf][ra1 * 64 + (ko ^ ((ra1 & 7) << 3))];
      #pragma unroll
      for (int fn = 0; fn < FN; ++fn) {
        const int rb = wn * (BN / 2) + fn * 16 + (lane & 15);
        short8 bf = *(const short8*)&smB[buf][rb * 64 + (ko ^ ((rb & 7) << 3))];
        acc[0][fn] = __builtin_amdgcn_mfma_f32_16x16x32_bf16(af0, bf, acc[0][fn], 0, 0, 0);
        acc[1][fn] = __builtin_amdgcn_mfma_f32_16x16x32_bf16(af1, bf, acc[1][fn], 0, 0, 0);
      }
    }
  };

  const int nkt = d.K >> 6;
  stageA(0, 0); stageB(0, 0);
  __syncthreads();
  for (int kt = 0; kt < nkt; ++kt) {
    const int cur = kt & 1;
    if (kt + 1 < nkt) { stageA(cur ^ 1, (kt + 1) << 6); stageB(cur ^ 1, (kt + 1) << 6); }
    compute(cur);
    __syncthreads();   // drains prefetch (had full compute phase to land) + protects buffer reuse
  }

  // epilogue: C/D layout col=lane&15, row=(lane>>4)*4+reg
  float nllSum = 0.f;
  #pragma unroll
  for (int fm = 0; fm < 2; ++fm)
    #pragma unroll
    for (int fn = 0; fn < FN; ++fn)
      #pragma unroll
      for (int j = 0; j < 4; ++j) {
        const int row = wm * 32 + fm * 16 + (lane >> 4) * 4 + j;
        const int col = wn * (BN / 2) + fn * 16 + (lane & 15);
        const int gm = mBase + row, gn = nBase + col;
        if (gn >= d.nValid) continue;
        float v = acc[fm][fn][j];
        if (bias) v += bias[bOff + col];
        switch (d.epi) {
          case EPI_RELU_BF16: d.outB[(long)gm * d.ldo + gn] = f2bf(fmaxf(v, 0.f)); break;
          case EPI_F32:       d.outF[(long)gm * d.ldo + gn] = v; break;
          case EPI_ATOMF32:   atomicAdd(&d.outF[(long)gm * d.ldo + gn], v); break;
          case EPI_NLL: {
            // dm = sigmoid(v); clip(log dm,-100) = -min(sp(-v),100); clip(log1p(-dm),-100) = -min(sp(v),100)
            const float xv = d.Af[(long)gm * XD_ + gn];
            nllSum += xv * fminf(spf(-v), 100.f) + (1.f - xv) * fminf(spf(v), 100.f);
          } break;
        }
      }
  if (d.epi == EPI_NLL) {
    #pragma unroll
    for (int o = 32; o; o >>= 1) nllSum += __shfl_down(nllSum, o, 64);
    if (lane == 0) rs[wv] = nllSum;
    __syncthreads();
    if (tid == 0) atomicAdd(d.red, rs[0] + rs[1] + rs[2] + rs[3]);
  }
}

// ---------------- fused z = eps*softplus(es)+em  ->  phi_z = relu(z@Wzp^T+bzp)  (K=128, 64x64 tiles) ----
// 128-col LDS tiles: element (r,c) at idx r*128 + (c ^ ((r&15)<<3)).
__global__ __launch_bounds__(256, 2)
void k_phiz(const float* emes, const float* eps_t, const u16* Wzp, const float* bzp, u16* phiz) {
  __shared__ u16 zA[64 * 128];
  __shared__ u16 wB[64 * 128];
  const int bid = blockIdx.x;
  const int tm = bid >> 5, tn = bid & 31;
  const int mBase = tm * 64, nBase = tn * 64;
  const int tid = threadIdx.x, lane = tid & 63, wv = tid >> 6;
  #pragma unroll
  for (int it = 0; it < 4; ++it) {
    const int e = it * 2048 + wv * 512 + lane * 8;
    const int r = e >> 7;
    const int s = (e & 127) >> 3;
    const int srcC = (s ^ (r & 15)) * 8;
    gl_lds16(Wzp + (long)(nBase + r) * 128 + srcC, &wB[it * 2048 + wv * 512]);
  }
  for (int i = tid; i < 64 * 16; i += 256) {
    const int m = i >> 4, j0 = (i & 15) * 8;
    const int gm = mBase + m;
    const floatx4* pe = (const floatx4*)(emes + gm * 256 + j0);
    const floatx4* pv = (const floatx4*)(emes + gm * 256 + 128 + j0);
    const floatx4* pp = (const floatx4*)(eps_t + (long)gm * 128 + j0);
    floatx4 em0 = pe[0], em1 = pe[1], es0 = pv[0], es1 = pv[1], ep0 = pp[0], ep1 = pp[1];
    short8 v;
    #pragma unroll
    for (int j = 0; j < 4; ++j) v[j] = (short)f2bf(ep0[j] * spf(es0[j]) + em0[j]);
    #pragma unroll
    for (int j = 0; j < 4; ++j) v[4 + j] = (short)f2bf(ep1[j] * spf(es1[j]) + em1[j]);
    *(short8*)&zA[m * 128 + (j0 ^ ((m & 15) << 3))] = v;
  }
  __syncthreads();
  const int wm = wv >> 1, wn = wv & 1;
  floatx4 acc[2][2];
  #pragma unroll
  for (int a = 0; a < 2; ++a)
    #pragma unroll
    for (int b = 0; b < 2; ++b) acc[a][b] = (floatx4){0.f, 0.f, 0.f, 0.f};
  #pragma unroll
  for (int ks = 0; ks < 4; ++ks) {
    const int ko = ks * 32 + (lane >> 4) * 8;
    const int ra0 = wm * 32 + (lane & 15), ra1 = ra0 + 16;
    short8 a0 = *(const short8*)&zA[ra0 * 128 + (ko ^ ((ra0 & 15) << 3))];
    short8 a1 = *(const short8*)&zA[ra1 * 128 + (ko ^ ((ra1 & 15) << 3))];
    #pragma unroll
    for (int fn = 0; fn < 2; ++fn) {
      const int rb = wn * 32 + fn * 16 + (lane & 15);
      short8 bf = *(const short8*)&wB[rb * 128 + (ko ^ ((rb & 15) << 3))];
      acc[0][fn] = __builtin_amdgcn_mfma_f32_16x16x32_bf16(a0, bf, acc[0][fn], 0, 0, 0);
      acc[1][fn] = __builtin_amdgcn_mfma_f32_16x16x32_bf16(a1, bf, acc[1][fn], 0, 0, 0);
    }
  }
  #pragma unroll
  for (int fm = 0; fm < 2; ++fm)
    #pragma unroll
    for (int fn = 0; fn < 2; ++fn)
      #pragma unroll
      for (int j = 0; j < 4; ++j) {
        const int row = wm * 32 + fm * 16 + (lane >> 4) * 4 + j;
        const int col = wn * 32 + fn * 16 + (lane & 15);
        phiz[(long)(mBase + row) * HD_ + nBase + col] = f2bf(fmaxf(acc[fm][fn][j] + bzp[nBase + col], 0.f));
      }
}

// ---------------- host ----------------
extern "C" void kernel_launch(void* const* d_in, const int* in_sizes, int n_in,
                              void* d_out, int out_size, void* d_ws, size_t ws_size,
                              hipStream_t stream) {
  const float* x   = (const float*)d_in[0];
  const float* eps = (const float*)d_in[1];
  const float* W1x = (const float*)d_in[2];  const float* b1x = (const float*)d_in[3];
  const float* W2x = (const float*)d_in[4];  const float* b2x = (const float*)d_in[5];
  const float* Wzp = (const float*)d_in[6];  const float* bzp = (const float*)d_in[7];
  const float* Wpr = (const float*)d_in[8];  const float* bpr = (const float*)d_in[9];
  const float* Wpm = (const float*)d_in[10]; const float* bpm = (const float*)d_in[11];
  const float* Wps = (const float*)d_in[12]; const float* bps = (const float*)d_in[13];
  const float* We1 = (const float*)d_in[14]; const float* be1 = (const float*)d_in[15];
  const float* We2 = (const float*)d_in[16]; const float* be2 = (const float*)d_in[17];
  const float* Wem = (const float*)d_in[18]; const float* bem = (const float*)d_in[19];
  const float* Wes = (const float*)d_in[20]; const float* bes = (const float*)d_in[21];
  const float* Wd1 = (const float*)d_in[22]; const float* bd1 = (const float*)d_in[23];
  const float* Wd2 = (const float*)d_in[24]; const float* bd2 = (const float*)d_in[25];
  const float* Wdm = (const float*)d_in[26]; const float* bdm = (const float*)d_in[27];
  const float* Wih = (const float*)d_in[28]; const float* bih = (const float*)d_in[29];
  const float* Whh = (const float*)d_in[30]; const float* bhh = (const float*)d_in[31];
  float* out = (float*)d_out;

  char* base = (char*)d_ws; size_t off = 0;
  auto alc = [&](size_t bytes) -> void* {
    void* r = base + off; off = (off + bytes + 255) & ~(size_t)255; return r;
  };
  // bf16 weights
  u16* W1xb = (u16*)alc((size_t)2048 * XDP_ * 2);
  u16* W2xb = (u16*)alc((size_t)2048 * 2048 * 2);
  u16* Wzpb = (u16*)alc((size_t)2048 * 128 * 2);
  u16* Wprb = (u16*)alc((size_t)2048 * 2048 * 2);
  u16* Wpmb = (u16*)alc((size_t)128 * 2048 * 2);
  u16* Wpsb = (u16*)alc((size_t)128 * 2048 * 2);
  u16* We1b = (u16*)alc((size_t)2048 * 4096 * 2);
  u16* We2b = (u16*)alc((size_t)2048 * 2048 * 2);
  u16* Wemb = (u16*)alc((size_t)128 * 2048 * 2);
  u16* Wesb = (u16*)alc((size_t)128 * 2048 * 2);
  u16* Wd1b = (u16*)alc((size_t)2048 * 4096 * 2);
  u16* Wd2b = (u16*)alc((size_t)2048 * 2048 * 2);
  u16* Wdmb = (u16*)alc((size_t)896 * 2048 * 2);   // N-padded 784->896, pad rows zero
  u16* Wihb = (u16*)alc((size_t)6144 * 4096 * 2);
  u16* Whhb = (u16*)alc((size_t)6144 * 2048 * 2);
  // activations
  u16* phixA   = (u16*)alc((size_t)B_ * HD_ * 2);
  u16* phixB   = (u16*)alc((size_t)B_ * HD_ * 2);
  u16* ph1     = (u16*)alc((size_t)B_ * HD_ * 2);
  float* h     = (float*)alc((size_t)B_ * HD_ * 4);
  u16* hbf     = (u16*)alc((size_t)B_ * HD_ * 2);
  u16* prior_bf= (u16*)alc((size_t)B_ * HD_ * 2);
  u16* enc1_bf = (u16*)alc((size_t)B_ * HD_ * 2);
  u16* enc_bf  = (u16*)alc((size_t)B_ * HD_ * 2);
  u16* dec1_bf = (u16*)alc((size_t)B_ * HD_ * 2);
  u16* dec_bf  = (u16*)alc((size_t)B_ * HD_ * 2);
  u16* phiz_bf = (u16*)alc((size_t)B_ * HD_ * 2);
  float* pmps  = (float*)alc((size_t)B_ * 256 * 4);
  float* emes  = (float*)alc((size_t)B_ * 256 * 4);
  float* gi    = (float*)alc((size_t)B_ * GD_ * 4);
  float* gh    = (float*)alc((size_t)B_ * GD_ * 4);
  if (off > ws_size) return;   // workspace too small -> loud validation failure, not corruption

  // ---- convert weights to bf16, zero h/h_bf/emes/out ----
  {
    ConvArgs ca; memset(&ca, 0, sizeof(ca));
    int ns = 0;
    auto seg = [&](const float* s, u16* dst, int dR, int dC, int sR, int sC) {
      ca.s[ns].src = s; ca.s[ns].dst = dst; ca.s[ns].dR = dR; ca.s[ns].dC = dC; ca.s[ns].sR = sR; ca.s[ns].sC = sC; ++ns;
    };
    seg(W1x, W1xb, 2048, XDP_, 2048, XD_);
    seg(W2x, W2xb, 2048, 2048, 2048, 2048);
    seg(Wzp, Wzpb, 2048, 128, 2048, 128);
    seg(Wpr, Wprb, 2048, 2048, 2048, 2048);
    seg(Wpm, Wpmb, 128, 2048, 128, 2048);
    seg(Wps, Wpsb, 128, 2048, 128, 2048);
    seg(We1, We1b, 2048, 4096, 2048, 4096);
    seg(We2, We2b, 2048, 2048, 2048, 2048);
    seg(Wem, Wemb, 128, 2048, 128, 2048);
    seg(Wes, Wesb, 128, 2048, 128, 2048);
    seg(Wd1, Wd1b, 2048, 4096, 2048, 4096);
    seg(Wd2, Wd2b, 2048, 2048, 2048, 2048);
    seg(Wdm, Wdmb, 896, 2048, 784, 2048);
    seg(Wih, Wihb, 6144, 4096, 6144, 4096);
    seg(Whh, Whhb, 6144, 2048, 6144, 2048);
    ca.n = ns;
    ca.hz = h;   ca.hzN = (long)B_ * HD_;
    ca.zf = emes; ca.zfN = (long)B_ * 256;
    ca.zb = hbf; ca.zbN = (long)B_ * HD_;
    ca.out2 = out;
    k_convert<<<1024, 256, 0, stream>>>(ca);
  }

  auto initD = [](GemmDesc& d) { memset(&d, 0, sizeof(d)); d.kSplit = 1 << 30; };

  // ---- prologue: phi_x(0) ----
  {
    GemmArgs a; memset(&a, 0, sizeof(a));
    GemmDesc& d = a.d[0]; initD(d);
    d.aF32 = 1; d.Af = x; d.K = XDP_;
    d.W0 = W1xb; d.ldw0 = XDP_; d.bias0 = b1x;
    d.N = HD_; d.nSplit = HD_; d.nValid = HD_;
    d.outB = ph1; d.ldo = HD_; d.epi = EPI_RELU_BF16; d.blockStart = 0; d.nTilesN = 32;
    a.n = 1;
    k_gemm<<<128, 256, 0, stream>>>(a);
  }
  {
    GemmArgs a; memset(&a, 0, sizeof(a));
    GemmDesc& d = a.d[0]; initD(d);
    d.A0 = ph1; d.lda0 = HD_; d.K = HD_;
    d.W0 = W2xb; d.ldw0 = HD_; d.bias0 = b2x;
    d.N = HD_; d.nSplit = HD_; d.nValid = HD_;
    d.outB = phixA; d.ldo = HD_; d.epi = EPI_RELU_BF16; d.blockStart = 0; d.nTilesN = 32;
    a.n = 1;
    k_gemm<<<128, 256, 0, stream>>>(a);
  }

  u16* phixCur = phixA; u16* phixNxt = phixB;
  for (int t = 0; t < T_; ++t) {
    // ---- S1: prior, enc1, gh  (64x64 tiles -> 640 blocks, ~2.5/CU) ----
    {
      GemmArgs a; memset(&a, 0, sizeof(a));
      int bs = 0, n = 0;
      { GemmDesc& d = a.d[n++]; initD(d);
        d.A0 = hbf; d.lda0 = HD_; d.W0 = Wprb; d.ldw0 = HD_; d.bias0 = bpr;
        d.N = HD_; d.K = HD_; d.nSplit = HD_; d.nValid = HD_;
        d.outB = prior_bf; d.ldo = HD_; d.epi = EPI_RELU_BF16; d.blockStart = bs; d.nTilesN = 32; bs += 128; }
      { GemmDesc& d = a.d[n++]; initD(d);
        d.A0 = phixCur; d.lda0 = HD_; d.A1 = hbf; d.lda1 = HD_; d.kSplit = HD_;
        d.W0 = We1b; d.ldw0 = 4096; d.bias0 = be1;
        d.N = HD_; d.K = 4096; d.nSplit = HD_; d.nValid = HD_;
        d.outB = enc1_bf; d.ldo = HD_; d.epi = EPI_RELU_BF16; d.blockStart = bs; d.nTilesN = 32; bs += 128; }
      { GemmDesc& d = a.d[n++]; initD(d);
        d.A0 = hbf; d.lda0 = HD_; d.W0 = Whhb; d.ldw0 = HD_; d.bias0 = bhh;
        d.N = GD_; d.K = HD_; d.nSplit = GD_; d.nValid = GD_;
        d.outF = gh; d.ldo = GD_; d.epi = EPI_F32; d.blockStart = bs; d.nTilesN = 96; bs += 384; }
      a.n = n;
      k_gemm<<<bs, 256, 0, stream>>>(a);
    }
    // ---- S2: enc2, pm/ps ----
    {
      GemmArgs a; memset(&a, 0, sizeof(a));
      int bs = 0, n = 0;
      { GemmDesc& d = a.d[n++]; initD(d);
        d.A0 = enc1_bf; d.lda0 = HD_; d.W0 = We2b; d.ldw0 = HD_; d.bias0 = be2;
        d.N = HD_; d.K = HD_; d.nSplit = HD_; d.nValid = HD_;
        d.outB = enc_bf; d.ldo = HD_; d.epi = EPI_RELU_BF16; d.blockStart = bs; d.nTilesN = 32; bs += 128; }
      { GemmDesc& d = a.d[n++]; initD(d);
        d.A0 = prior_bf; d.lda0 = HD_;
        d.W0 = Wpmb; d.ldw0 = HD_; d.W1 = Wpsb; d.ldw1 = HD_; d.bias0 = bpm; d.bias1 = bps;
        d.N = 256; d.K = HD_; d.nSplit = 128; d.nValid = 256;
        d.outF = pmps; d.ldo = 256; d.epi = EPI_F32; d.blockStart = bs; d.nTilesN = 4; bs += 16; }
      a.n = n;
      k_gemm<<<bs, 256, 0, stream>>>(a);
    }
    // ---- S3: em/es (split-K x8, atomic into zeroed emes) + NLL of step t-1 ----
    {
      GemmArgs a; memset(&a, 0, sizeof(a));
      int bs = 0, n = 0;
      for (int c = 0; c < 8; ++c) {
        GemmDesc& d = a.d[n++]; initD(d);
        d.A0 = enc_bf + c * 256; d.lda0 = HD_;
        d.W0 = Wemb + c * 256; d.ldw0 = HD_; d.W1 = Wesb + c * 256; d.ldw1 = HD_;
        d.bias0 = (c == 0) ? bem : nullptr; d.bias1 = (c == 0) ? bes : nullptr;
        d.N = 256; d.K = 256; d.nSplit = 128; d.nValid = 256;
        d.outF = emes; d.ldo = 256; d.epi = EPI_ATOMF32; d.blockStart = bs; d.nTilesN = 4; bs += 16;
      }
      if (t > 0) {
        GemmDesc& d = a.d[n++]; initD(d);
        d.A0 = dec_bf; d.lda0 = HD_; d.W0 = Wdmb; d.ldw0 = HD_; d.bias0 = bdm;
        d.N = 896; d.K = HD_; d.nSplit = 896; d.nValid = XD_;
        d.Af = x + (size_t)(t - 1) * B_ * XD_; d.red = out + 1;
        d.epi = EPI_NLL; d.blockStart = bs; d.nTilesN = 14; bs += 56;
      }
      a.n = n;
      k_gemm<<<bs, 256, 0, stream>>>(a);
    }
    // ---- S4: z + phi_z ----
    k_phiz<<<128, 256, 0, stream>>>(emes, eps + (size_t)t * B_ * ZD_, Wzpb, bzp, phiz_bf);
    // ---- S5: dec1, gi  (+ phi_x stage1 for t+1) -> 640 blocks ----
    {
      GemmArgs a; memset(&a, 0, sizeof(a));
      int bs = 0, n = 0;
      { GemmDesc& d = a.d[n++]; initD(d);
        d.A0 = phiz_bf; d.lda0 = HD_; d.A1 = hbf; d.lda1 = HD_; d.kSplit = HD_;
        d.W0 = Wd1b; d.ldw0 = 4096; d.bias0 = bd1;
        d.N = HD_; d.K = 4096; d.nSplit = HD_; d.nValid = HD_;
        d.outB = dec1_bf; d.ldo = HD_; d.epi = EPI_RELU_BF16; d.blockStart = bs; d.nTilesN = 32; bs += 128; }
      { GemmDesc& d = a.d[n++]; initD(d);
        d.A0 = phixCur; d.lda0 = HD_; d.A1 = phiz_bf; d.lda1 = HD_; d.kSplit = HD_;
        d.W0 = Wihb; d.ldw0 = 4096; d.bias0 = bih;
        d.N = GD_; d.K = 4096; d.nSplit = GD_; d.nValid = GD_;
        d.outF = gi; d.ldo = GD_; d.epi = EPI_F32; d.blockStart = bs; d.nTilesN = 96; bs += 384; }
      if (t < T_ - 1) {
        GemmDesc& d = a.d[n++]; initD(d);
        d.aF32 = 1; d.Af = x + (size_t)(t + 1) * B_ * XD_; d.K = XDP_;
        d.W0 = W1xb; d.ldw0 = XDP_; d.bias0 = b1x;
        d.N = HD_; d.nSplit = HD_; d.nValid = HD_;
        d.outB = ph1; d.ldo = HD_; d.epi = EPI_RELU_BF16; d.blockStart = bs; d.nTilesN = 32; bs += 128;
      }
      a.n = n;
      k_gemm<<<bs, 256, 0, stream>>>(a);
    }
    // ---- S6: dec2, phi_x stage2 (t+1), GRU combine, KLD ----
    {
      GemmArgs a; memset(&a, 0, sizeof(a));
      int bs = 0, n = 0;
      { GemmDesc& d = a.d[n++]; initD(d);
        d.A0 = dec1_bf; d.lda0 = HD_; d.W0 = Wd2b; d.ldw0 = HD_; d.bias0 = bd2;
        d.N = HD_; d.K = HD_; d.nSplit = HD_; d.nValid = HD_;
        d.outB = dec_bf; d.ldo = HD_; d.epi = EPI_RELU_BF16; d.blockStart = bs; d.nTilesN = 32; bs += 128; }
      if (t < T_ - 1) {
        GemmDesc& d = a.d[n++]; initD(d);
        d.A0 = ph1; d.lda0 = HD_; d.K = HD_;
        d.W0 = W2xb; d.ldw0 = HD_; d.bias0 = b2x;
        d.N = HD_; d.nSplit = HD_; d.nValid = HD_;
        d.outB = phixNxt; d.ldo = HD_; d.epi = EPI_RELU_BF16; d.blockStart = bs; d.nTilesN = 32; bs += 128;
      }
      { GemmDesc& d = a.d[n++]; initD(d);
        d.epi = EPI_GRU; d.pf0 = gi; d.pf1 = gh; d.outF = h; d.outB = hbf;
        d.blockStart = bs; d.nTilesN = 64; bs += 64; }
      { GemmDesc& d = a.d[n++]; initD(d);
        d.epi = EPI_KLD; d.pf0 = pmps; d.pf1 = emes; d.red = out;
        d.blockStart = bs; d.nTilesN = 8; bs += 8; }
      a.n = n;
      k_gemm<<<bs, 256, 0, stream>>>(a);
    }
    { u16* tmp = phixCur; phixCur = phixNxt; phixNxt = tmp; }
  }
  // ---- final dm/NLL for t = T-1 ----
  {
    GemmArgs a; memset(&a, 0, sizeof(a));
    GemmDesc& d = a.d[0]; initD(d);
    d.A0 = dec_bf; d.lda0 = HD_; d.W0 = Wdmb; d.ldw0 = HD_; d.bias0 = bdm;
    d.N = 896; d.K = HD_; d.nSplit = 896; d.nValid = XD_;
    d.Af = x + (size_t)(T_ - 1) * B_ * XD_; d.red = out + 1;
    d.epi = EPI_NLL; d.blockStart = 0; d.nTilesN = 14;
    a.n = 1;
    k_gemm<<<56, 256, 0, stream>>>(a);
  }
}